// Round 4
// baseline (164.329 us; speedup 1.0000x reference)
//
#include <hip/hip_runtime.h>
#include <hip/hip_cooperative_groups.h>
#include <math.h>

namespace cg = cooperative_groups;

#define WL   140
#define OFC  118
#define TDN  21
#define COUT 10
#define KS   9
#define IW_SZ (OFC * OFC)       // 13924

// ws layout (floats)
#define PROJ_STRIDE 6848
#define KP_OFF      1888
#define VP_OFF      4368
#define WS_ATT_A    13696
#define WS_ATT_B    13824
#define WS_FEATS    13952

// proj work decomposition
#define SIDE  6844              // dots per td side (16+21+21)*118
#define QN    1888              // 16*118
#define QKN   4366              // QN + 21*118
#define NPROJ 13688             // 2*SIDE
#define NPBLK 12                // proj blocks
#define NPW   (NPBLK * 8)       // proj waves

struct Params {
    const float *x;
    const float *tdA_in_w, *tdA_in_b, *tdA_out_w, *tdA_out_b;
    const float *tdB_in_w, *tdB_in_b, *tdB_out_w, *tdB_out_b;
    const float *cm_in_w, *cm_in_b, *cm_out_w, *cm_out_b;
    const float *projA_w, *projB_w, *conv_w, *conv_b;
    const float *fc1_w, *fc1_b, *fc2_w, *fc2_b;
    float *ws, *out;
};

struct P2Sm {                     // blocks 0,1 phase 2 (attn/select)
    float attn[16][TDN];
    float acs[22];                // padded so avcs is 8B-aligned
    float avcs[OFC];
    float colsum[OFC];
    float Ssum[16];
    float avsel[OFC];
    int   sel;
};

struct BrSm {                     // blocks 12..15
    float arow[OFC];
    float pv[16];
    float eeg_s[16][OFC];
    float w_inT[16][48];
    float b_in[48];
    float tv[3][16];
    float w_out[16][16];
    float b_out[16];
    float cw[COUT * 16 * KS];
    float cb[COUT];
    float qpS[OFC][17];
    float kpS[OFC][17];
    float vpS[OFC][17];
    float part_m[4][128];
    float part_l[4][128];
    float part_acc[4][OFC][17];
    float o2[OFC][17];
    float y[COUT][22];
};

struct HdSm { float f[40]; float h[40]; };

union alignas(16) Sm { P2Sm p2; BrSm b; HdSm h; };   // ~88 KB

__device__ inline float wred(float v) {
    #pragma unroll
    for (int off = 32; off; off >>= 1) v += __shfl_xor(v, off);
    return v;
}

// ---------------------------------------------------------------------------
// Phase 1a (blocks 0..11): td q/k/v projections, wave-per-dot, weights from
// global (coalesced float2 per lane), butterfly reduce.
// ---------------------------------------------------------------------------
__device__ void proj_phase(int blk, int tid, const Params& p)
{
    const int gw   = blk * 8 + (tid >> 6);
    const int lane = tid & 63;
    const float rs = 1.0f / sqrtf(118.0f);

    for (int d = gw; d < NPROJ; d += NPW) {
        int rr = d, b = 0;
        if (rr >= SIDE) { b = 1; rr -= SIDE; }
        int sec;
        if (rr < QN)       { sec = 0; }
        else if (rr < QKN) { sec = 1; rr -= QN; }
        else               { sec = 2; rr -= QKN; }
        const int r = rr / OFC, o = rr - r * OFC;

        const float* iw = (b ? p.tdB_in_w : p.tdA_in_w) + sec * IW_SZ + o * OFC;
        const int j0 = lane * 2;
        float s = 0.f;
        if (j0 < OFC) {
            float2 wv = *(const float2*)(iw + j0);     // o*118 even -> aligned
            float a0, a1;
            if (sec == 0) {
                const float* er = p.x + (1 + r) * WL + (WL - OFC);
                a0 = er[j0]; a1 = er[j0 + 1];
            } else {
                const float* wr = p.x + (b ? 17 * WL : 0) + r;
                a0 = wr[j0]; a1 = wr[j0 + 1];
            }
            s = a0 * wv.x + a1 * wv.y;
        }
        s = wred(s);
        if (lane == 0) {
            const float* ib = (b ? p.tdB_in_b : p.tdA_in_b);
            float res = s + ib[sec * OFC + o];
            if (sec == 0) res *= rs;
            p.ws[b * PROJ_STRIDE
                 + (sec == 0 ? 0 : (sec == 1 ? KP_OFF : VP_OFF))
                 + r * OFC + o] = res;
        }
    }
    __threadfence();
}

// ---------------------------------------------------------------------------
// Phase 2 (blocks 0,1): scores + softmax + colsum-select + selected-row proj.
// qp/kp/vp read from ws (L2-hot); out_w read from global via wave-reduce.
// ---------------------------------------------------------------------------
__device__ void td_phase2(int b, int tid, const Params& p, P2Sm& s)
{
    const int wid = tid >> 6, lane = tid & 63;
    const float* base  = p.ws + b * PROJ_STRIDE;
    const float* out_w = b ? p.tdB_out_w : p.tdA_out_w;
    const float* out_b = b ? p.tdB_out_b : p.tdA_out_b;

    // scores 16x21, wave-per-dot
    for (int d = wid; d < 16 * TDN; d += 8) {
        int i = d / TDN, t = d - i * TDN;
        const float* q = base + i * OFC;
        const float* k = base + KP_OFF + t * OFC;
        int j0 = lane * 2;
        float sc = 0.f;
        if (j0 < OFC) {
            float2 qv = *(const float2*)(q + j0);
            float2 kv = *(const float2*)(k + j0);
            sc = qv.x * kv.x + qv.y * kv.y;
        }
        sc = wred(sc);
        if (lane == 0) s.attn[i][t] = sc;
    }
    __syncthreads();

    if (tid < 16) {
        float m = s.attn[tid][0];
        for (int t = 1; t < TDN; ++t) m = fmaxf(m, s.attn[tid][t]);
        float l = 0.f;
        for (int t = 0; t < TDN; ++t) {
            float pp = __expf(s.attn[tid][t] - m);
            s.attn[tid][t] = pp;
            l += pp;
        }
        float inv = 1.f / l;
        for (int t = 0; t < TDN; ++t) s.attn[tid][t] *= inv;
    }
    __syncthreads();

    if (tid < TDN) {
        float a = 0.f;
        for (int i = 0; i < 16; ++i) a += s.attn[i][tid];
        s.acs[tid] = a;
    }
    __syncthreads();

    if (tid < OFC) {                       // avcs[o] = sum_t acs[t]*vp[t][o], coalesced
        float a = 0.f;
        for (int t = 0; t < TDN; ++t) a += s.acs[t] * base[VP_OFF + t * OFC + tid];
        s.avcs[tid] = a;
    }
    __syncthreads();

    for (int d = wid; d < OFC; d += 8) {   // colsum[o] = avcs . out_w[o] + 16*b[o]
        int j0 = lane * 2;
        float sc = 0.f;
        if (j0 < OFC) {
            float2 av = *(const float2*)(&s.avcs[j0]);
            float2 wv = *(const float2*)(out_w + d * OFC + j0);
            sc = av.x * wv.x + av.y * wv.y;
        }
        sc = wred(sc);
        if (lane == 0) s.colsum[d] = sc + 16.f * out_b[d];
    }
    __syncthreads();

    for (int d = wid; d < 16; d += 8) {    // Ssum[i] = eeg[i] . colsum
        const float* er = p.x + (1 + d) * WL + (WL - OFC);
        int j0 = lane * 2;
        float sc = 0.f;
        if (j0 < OFC) sc = er[j0] * s.colsum[j0] + er[j0 + 1] * s.colsum[j0 + 1];
        sc = wred(sc);
        if (lane == 0) s.Ssum[d] = sc;
    }
    __syncthreads();

    if (tid == 0) {
        int best = 0; float bv = s.Ssum[0];
        for (int i = 1; i < 16; ++i)
            if (s.Ssum[i] > bv) { bv = s.Ssum[i]; best = i; }   // first-max
        s.sel = best;
    }
    __syncthreads();

    if (tid < OFC) {                       // avsel[o] = sum_t attn[sel][t]*vp[t][o]
        float a = 0.f;
        for (int t = 0; t < TDN; ++t) a += s.attn[s.sel][t] * base[VP_OFF + t * OFC + tid];
        s.avsel[tid] = a;
    }
    __syncthreads();

    for (int d = wid; d < OFC; d += 8) {   // selected row out-projection
        int j0 = lane * 2;
        float sc = 0.f;
        if (j0 < OFC) {
            float2 av = *(const float2*)(&s.avsel[j0]);
            float2 wv = *(const float2*)(out_w + d * OFC + j0);
            sc = av.x * wv.x + av.y * wv.y;
        }
        sc = wred(sc);
        if (lane == 0) p.ws[(b ? WS_ATT_B : WS_ATT_A) + d] = sc + out_b[d];
    }
    __threadfence();
}

// ---------------------------------------------------------------------------
// Phase 1b (blocks 12..15): branch prestage + eeg-side q/k/v sections.
// ---------------------------------------------------------------------------
__device__ void br_pre(int br, int tid, const Params& p, BrSm& s)
{
    for (int e = tid; e < 16 * OFC; e += 512) {
        int r = e / OFC, c = e % OFC;
        s.eeg_s[r][c] = p.x[(1 + r) * WL + (WL - OFC) + c];
    }
    for (int e = tid; e < 768; e += 512) {
        int q = e / 16, r = e % 16;
        s.w_inT[r][q] = p.cm_in_w[br * 768 + e];
    }
    if (tid < 48) s.b_in[tid] = p.cm_in_b[br * 48 + tid];
    if (tid >= 64 && tid < 320) {
        int e = tid - 64;
        s.w_out[e >> 4][e & 15] = p.cm_out_w[br * 256 + e];
    }
    if (tid >= 384 && tid < 400) s.b_out[tid - 384] = p.cm_out_b[br * 16 + (tid - 384)];
    for (int e = tid; e < COUT * 16 * KS; e += 512) s.cw[e] = p.conv_w[br * 1440 + e];
    if (tid >= 400 && tid < 400 + COUT) s.cb[tid - 400] = p.conv_b[br * COUT + (tid - 400)];
    {
        const float* pvg = (br < 2) ? p.projA_w : p.projB_w;
        if (tid >= 416 && tid < 432) s.pv[tid - 416] = pvg[tid - 416];
    }
    __syncthreads();

    if (tid < 48) {
        float a = 0.f;
        #pragma unroll
        for (int r = 0; r < 16; ++r) a += s.pv[r] * s.w_inT[r][tid];
        s.tv[tid / 16][tid % 16] = a;
    }
    __syncthreads();

    const bool d_r1 = (br == 0 || br == 3);
    for (int e = tid; e < 3 * OFC * 16; e += 512) {
        int sec = e / (OFC * 16);
        int rem = e - sec * OFC * 16;
        int j = rem >> 4, o = rem & 15;
        bool r1 = (sec == 0) ? d_r1 : !d_r1;
        if (!r1) {
            float a = 0.f;
            #pragma unroll
            for (int r = 0; r < 16; ++r) a += s.eeg_s[r][j] * s.w_inT[r][sec * 16 + o];
            a += s.b_in[sec * 16 + o];
            if (sec == 0) a *= 0.25f;
            float* dst = (sec == 0) ? &s.qpS[0][0] : (sec == 1 ? &s.kpS[0][0] : &s.vpS[0][0]);
            dst[j * 17 + o] = a;
        }
    }
}

// ---------------------------------------------------------------------------
// Phase 3 (blocks 12..15): rank-1 qkv, flash attention, out-proj, conv, max.
// ---------------------------------------------------------------------------
__device__ void br_main(int br, int tid, const Params& p, BrSm& s)
{
    const bool d_r1 = (br == 0 || br == 3);
    const float* ar = p.ws + ((br < 2) ? WS_ATT_A : WS_ATT_B);
    for (int j = tid; j < OFC; j += 512) s.arow[j] = ar[j];
    __syncthreads();

    for (int e = tid; e < 3 * OFC * 16; e += 512) {
        int sec = e / (OFC * 16);
        int rem = e - sec * OFC * 16;
        int j = rem >> 4, o = rem & 15;
        bool r1 = (sec == 0) ? d_r1 : !d_r1;
        if (r1) {
            float a = s.tv[sec][o] * s.arow[j] + s.b_in[sec * 16 + o];
            if (sec == 0) a *= 0.25f;
            float* dst = (sec == 0) ? &s.qpS[0][0] : (sec == 1 ? &s.kpS[0][0] : &s.vpS[0][0]);
            dst[j * 17 + o] = a;
        }
    }
    __syncthreads();

    const int g = tid >> 7, j = tid & 127;
    float q[16], acc[16];
    float m = -INFINITY, l = 0.f;
    #pragma unroll
    for (int r = 0; r < 16; ++r) acc[r] = 0.f;

    if (j < OFC) {
        #pragma unroll
        for (int r = 0; r < 16; ++r) q[r] = s.qpS[j][r];
        const int t0 = (g * OFC) >> 2, t1 = ((g + 1) * OFC) >> 2;
        for (int t = t0; t < t1; ++t) {
            const float* kr = &s.kpS[t][0];
            float sc = 0.f;
            #pragma unroll
            for (int r = 0; r < 16; ++r) sc += q[r] * kr[r];
            float mn = fmaxf(m, sc);
            float c  = __expf(m - mn);
            float pp = __expf(sc - mn);
            l = l * c + pp;
            const float* vr = &s.vpS[t][0];
            #pragma unroll
            for (int r = 0; r < 16; ++r) acc[r] = acc[r] * c + pp * vr[r];
            m = mn;
        }
        s.part_m[g][j] = m;
        s.part_l[g][j] = l;
        #pragma unroll
        for (int r = 0; r < 16; ++r) s.part_acc[g][j][r] = acc[r];
    }
    __syncthreads();

    if (tid < OFC) {
        float m0 = s.part_m[0][tid], m1 = s.part_m[1][tid];
        float m2 = s.part_m[2][tid], m3 = s.part_m[3][tid];
        float mm = fmaxf(fmaxf(m0, m1), fmaxf(m2, m3));
        float c0 = __expf(m0 - mm), c1 = __expf(m1 - mm);
        float c2 = __expf(m2 - mm), c3 = __expf(m3 - mm);
        float ll = c0 * s.part_l[0][tid] + c1 * s.part_l[1][tid]
                 + c2 * s.part_l[2][tid] + c3 * s.part_l[3][tid];
        float inv = 1.f / ll;
        float orow[16];
        #pragma unroll
        for (int r = 0; r < 16; ++r)
            orow[r] = (c0 * s.part_acc[0][tid][r] + c1 * s.part_acc[1][tid][r]
                     + c2 * s.part_acc[2][tid][r] + c3 * s.part_acc[3][tid][r]) * inv;
        for (int c = 0; c < 16; ++c) {
            float a = s.b_out[c];
            #pragma unroll
            for (int d = 0; d < 16; ++d) a += orow[d] * s.w_out[c][d];
            s.o2[tid][c] = a;
        }
    }
    __syncthreads();

    // conv: thread = (channel, 5-position group); 13-wide window in registers
    if (tid < COUT * 22) {
        int c = tid / 22, grp = tid - (tid / 22) * 22;
        int pbase = grp * 5;
        float acc5[5];
        #pragma unroll
        for (int i = 0; i < 5; ++i) acc5[i] = s.cb[c];
        for (int mI = 0; mI < 16; ++mI) {
            float win[13];
            #pragma unroll
            for (int t = 0; t < 13; ++t) win[t] = s.o2[pbase + t][mI];
            #pragma unroll
            for (int k = 0; k < KS; ++k) {
                float wv = s.cw[(c * 16 + mI) * KS + k];
                #pragma unroll
                for (int i = 0; i < 5; ++i) acc5[i] += win[i + k] * wv;
            }
        }
        float mx = fmaxf(fmaxf(fmaxf(acc5[0], acc5[1]), fmaxf(acc5[2], acc5[3])), acc5[4]);
        s.y[c][grp] = fmaxf(mx, 0.f);      // relu(max) == max(relu)
    }
    __syncthreads();

    if (tid < COUT) {
        float mx = s.y[tid][0];
        for (int g2 = 1; g2 < 22; ++g2) mx = fmaxf(mx, s.y[tid][g2]);
        p.ws[WS_FEATS + br * COUT + tid] = mx;
    }
    __threadfence();
}

// ---------------------------------------------------------------------------
__global__ __launch_bounds__(512) void fused_net(Params p)
{
    __shared__ Sm sm;
    cg::grid_group grid = cg::this_grid();
    const int blk = blockIdx.x;
    const int tid = threadIdx.x;

    // phase 1: projections (blocks 0..11) || branch prestage (blocks 12..15)
    if (blk < NPBLK) proj_phase(blk, tid, p);
    else             br_pre(blk - NPBLK, tid, p, sm.b);
    grid.sync();

    // phase 2: attention + row-select (blocks 0,1)
    if (blk < 2) td_phase2(blk, tid, p, sm.p2);
    grid.sync();

    // phase 3: branches (blocks 12..15)
    if (blk >= NPBLK) br_main(blk - NPBLK, tid, p, sm.b);
    grid.sync();

    // phase 4: head (block 0)
    if (blk == 0) {
        __syncthreads();
        if (tid < 40) sm.h.f[tid] = p.ws[WS_FEATS + tid];
        __syncthreads();
        if (tid < 40) {
            float a = p.fc1_b[tid];
            for (int k = 0; k < 40; ++k) a += sm.h.f[k] * p.fc1_w[tid * 40 + k];
            sm.h.h[tid] = 1.f / (1.f + __expf(-a));
        }
        __syncthreads();
        if (tid < 2) {
            float a = p.fc2_b[tid];
            for (int k = 0; k < 40; ++k) a += sm.h.h[k] * p.fc2_w[tid * 40 + k];
            p.out[tid] = 1.f / (1.f + __expf(-a));
        }
    }
}

// ---------------------------------------------------------------------------
extern "C" void kernel_launch(void* const* d_in, const int* in_sizes, int n_in,
                              void* d_out, int out_size, void* d_ws, size_t ws_size,
                              hipStream_t stream) {
    Params prm;
    prm.x         = (const float*)d_in[0];
    prm.tdA_in_w  = (const float*)d_in[1];
    prm.tdA_in_b  = (const float*)d_in[2];
    prm.tdA_out_w = (const float*)d_in[3];
    prm.tdA_out_b = (const float*)d_in[4];
    prm.tdB_in_w  = (const float*)d_in[5];
    prm.tdB_in_b  = (const float*)d_in[6];
    prm.tdB_out_w = (const float*)d_in[7];
    prm.tdB_out_b = (const float*)d_in[8];
    prm.cm_in_w   = (const float*)d_in[9];
    prm.cm_in_b   = (const float*)d_in[10];
    prm.cm_out_w  = (const float*)d_in[11];
    prm.cm_out_b  = (const float*)d_in[12];
    prm.projA_w   = (const float*)d_in[13];
    prm.projB_w   = (const float*)d_in[14];
    prm.conv_w    = (const float*)d_in[15];
    prm.conv_b    = (const float*)d_in[16];
    prm.fc1_w     = (const float*)d_in[17];
    prm.fc1_b     = (const float*)d_in[18];
    prm.fc2_w     = (const float*)d_in[19];
    prm.fc2_b     = (const float*)d_in[20];
    prm.ws        = (float*)d_ws;
    prm.out       = (float*)d_out;

    void* args[] = { &prm };
    hipLaunchCooperativeKernel((const void*)fused_net, dim3(16), dim3(512),
                               args, 0, stream);
}

// Round 5
// 73.213 us; speedup vs baseline: 2.2445x; 2.2445x over previous
//
#include <hip/hip_runtime.h>
#include <hip/hip_cooperative_groups.h>
#include <math.h>

namespace cg = cooperative_groups;

#define WL   140
#define OFC  118
#define TDN  21
#define COUT 10
#define KS   9
#define IW_SZ (OFC * OFC)       // 13924

// ws layout (floats)
#define PROJ_STRIDE 6848
#define KP_OFF      1888
#define VP_OFF      4368
#define WS_ATT_A    13696
#define WS_ATT_B    13824
#define WS_FEATS    13952

#define NPBLK 12                // proj blocks (phase 1)

struct Params {
    const float *x;
    const float *tdA_in_w, *tdA_in_b, *tdA_out_w, *tdA_out_b;
    const float *tdB_in_w, *tdB_in_b, *tdB_out_w, *tdB_out_b;
    const float *cm_in_w, *cm_in_b, *cm_out_w, *cm_out_b;
    const float *projA_w, *projB_w, *conv_w, *conv_b;
    const float *fc1_w, *fc1_b, *fc2_w, *fc2_b;
    float *ws, *out;
};

struct TdSm {                     // blocks 0..11 (proj); 0,1 also run phase 2
    float wpad[59][122];          // weight strip, stride 122 (bank-optimal, 8B-aligned)
    float inp[21][120];           // eeg rows or wav windows
    float owpad[OFC][122];        // out_w padded (blocks 0,1 only)
    float qkv[PROJ_STRIDE];       // phase 2: qp|kp|vp staged from ws
    float attn[16][22];
    float acs[22];
    float avcs[120];
    float colsum[120];
    float Ssum[16];
    float avsel[120];
    int   sel;
};

struct BrSm {                     // blocks 12..15
    float arow[OFC];
    float pv[16];
    float eeg_s[16][OFC];
    float w_inT[16][48];
    float b_in[48];
    float tv[3][16];
    float w_out[16][16];
    float b_out[16];
    float cw[COUT * 16 * KS];
    float cb[COUT];
    float qpS[OFC][17];
    float kpS[OFC][17];
    float vpS[OFC][17];
    float part_m[4][128];
    float part_l[4][128];
    float part_acc[4][OFC][17];
    float o2[OFC][17];
    float y[COUT][22];
};

struct HdSm { float f[40]; float h[40]; };

union alignas(16) Sm { TdSm t; BrSm b; HdSm h; };   // ~127 KB < 160 KB

__device__ inline float wred(float v) {
    #pragma unroll
    for (int off = 32; off; off >>= 1) v += __shfl_xor(v, off);
    return v;
}

// ---------------------------------------------------------------------------
// Phase 1a (blocks 0..11): td projections. blk -> (side b, section, half).
// Each block: stage 59x118 weight strip (stride-122 LDS) + inputs; thread-per-
// output dot from LDS; coalesced write to ws. Blocks 0,1 prefetch out_w.
// ---------------------------------------------------------------------------
__device__ void td_proj(int blk, int tid, const Params& p, TdSm& s)
{
    const int b    = blk / 6;
    const int rem  = blk % 6;
    const int sec  = rem >> 1;          // 0=q,1=k,2=v
    const int half = rem & 1;
    const float* in_w = (b ? p.tdB_in_w : p.tdA_in_w) + sec * IW_SZ + half * 59 * OFC;
    const float* in_b = (b ? p.tdB_in_b : p.tdA_in_b) + sec * OFC + half * 59;
    const float* wav  = p.x + (b ? 17 * WL : 0);

    if (blk < 2) {                      // prefetch out_w for phase 2
        const float* ow = blk ? p.tdB_out_w : p.tdA_out_w;
        for (int e = tid; e < IW_SZ; e += 512) {
            int o = e / OFC, j = e - o * OFC;
            s.owpad[o][j] = ow[e];
        }
    }
    for (int e = tid; e < 59 * OFC; e += 512) {
        int o = e / OFC, j = e - o * OFC;
        s.wpad[o][j] = in_w[e];         // coalesced global read
    }
    if (sec == 0) {
        for (int e = tid; e < 16 * OFC; e += 512) {
            int r = e / OFC, c = e - (e / OFC) * OFC;
            s.inp[r][c] = p.x[(1 + r) * WL + (WL - OFC) + c];
        }
    } else {
        for (int e = tid; e < TDN * 120; e += 512) {
            int t = e / 120, j = e - (e / 120) * 120;    // t+j <= 139 < 140
            s.inp[t][j] = wav[t + j];
        }
    }
    __syncthreads();

    const int   R     = (sec == 0) ? 16 : TDN;
    const float scale = (sec == 0) ? (1.0f / sqrtf(118.0f)) : 1.0f;
    float* dst = p.ws + b * PROJ_STRIDE
               + (sec == 0 ? 0 : (sec == 1 ? KP_OFF : VP_OFF));

    for (int e = tid; e < R * 59; e += 512) {
        int r = e / 59, o = e - r * 59;
        const float2* a  = (const float2*)&s.inp[r][0];   // broadcast across lanes
        const float2* w2 = (const float2*)&s.wpad[o][0];  // consecutive rows
        float s0 = 0.f;
        #pragma unroll 4
        for (int j = 0; j < 59; ++j) {
            float2 u = a[j], w = w2[j];
            s0 += u.x * w.x + u.y * w.y;
        }
        dst[r * OFC + half * 59 + o] = (s0 + in_b[o]) * scale;
    }
    __threadfence();
}

// ---------------------------------------------------------------------------
// Phase 2 (blocks 0,1): scores + softmax + colsum row-select + selected row.
// qkv staged from ws; out_w already in LDS (owpad).
// ---------------------------------------------------------------------------
__device__ void td_phase2(int b, int tid, const Params& p, TdSm& s)
{
    const float* base  = p.ws + b * PROJ_STRIDE;
    const float* out_b = b ? p.tdB_out_b : p.tdA_out_b;
    const int wid = tid >> 6, lane = tid & 63;

    for (int e = tid; e < PROJ_STRIDE; e += 512) s.qkv[e] = base[e];
    __syncthreads();

    // scores 16x21 (dot-118, all LDS)
    if (tid < 16 * TDN) {
        int i = tid / TDN, t = tid - (tid / TDN) * TDN;
        const float2* q = (const float2*)&s.qkv[i * OFC];
        const float2* k = (const float2*)&s.qkv[KP_OFF + t * OFC];
        float sc = 0.f;
        #pragma unroll 4
        for (int j = 0; j < 59; ++j) {
            float2 u = q[j], v = k[j];
            sc += u.x * v.x + u.y * v.y;
        }
        s.attn[i][t] = sc;
    }
    __syncthreads();

    if (tid < 16) {                     // softmax rows
        float m = s.attn[tid][0];
        for (int t = 1; t < TDN; ++t) m = fmaxf(m, s.attn[tid][t]);
        float l = 0.f;
        for (int t = 0; t < TDN; ++t) {
            float pp = __expf(s.attn[tid][t] - m);
            s.attn[tid][t] = pp;
            l += pp;
        }
        float inv = 1.f / l;
        for (int t = 0; t < TDN; ++t) s.attn[tid][t] *= inv;
    }
    __syncthreads();

    if (tid < TDN) {                    // attn column sums
        float a = 0.f;
        for (int i = 0; i < 16; ++i) a += s.attn[i][tid];
        s.acs[tid] = a;
    }
    __syncthreads();

    if (tid < OFC) {                    // avcs[o] = sum_t acs[t]*vp[t][o]
        float a = 0.f;
        for (int t = 0; t < TDN; ++t) a += s.acs[t] * s.qkv[VP_OFF + t * OFC + tid];
        s.avcs[tid] = a;
    }
    __syncthreads();

    if (tid < OFC) {                    // colsum[o] = avcs . out_w[o] + 16*b[o]
        const float2* a  = (const float2*)&s.avcs[0];
        const float2* w2 = (const float2*)&s.owpad[tid][0];
        float a0 = 0.f;
        #pragma unroll 4
        for (int j = 0; j < 59; ++j) {
            float2 u = a[j], v = w2[j];
            a0 += u.x * v.x + u.y * v.y;
        }
        s.colsum[tid] = a0 + 16.f * out_b[tid];
    }
    __syncthreads();

    for (int d = wid; d < 16; d += 8) { // Ssum[i] = eeg[i] . colsum (wave-reduce)
        const float* er = p.x + (1 + d) * WL + (WL - OFC);
        int j0 = lane * 2;
        float sc = 0.f;
        if (j0 < OFC) {
            float2 ev = *(const float2*)(er + j0);
            float2 cv = *(const float2*)(&s.colsum[j0]);
            sc = ev.x * cv.x + ev.y * cv.y;
        }
        sc = wred(sc);
        if (lane == 0) s.Ssum[d] = sc;
    }
    __syncthreads();

    if (tid == 0) {
        int best = 0; float bv = s.Ssum[0];
        for (int i = 1; i < 16; ++i)
            if (s.Ssum[i] > bv) { bv = s.Ssum[i]; best = i; }   // first-max
        s.sel = best;
    }
    __syncthreads();

    if (tid < OFC) {                    // avsel[o] = sum_t attn[sel][t]*vp[t][o]
        float a = 0.f;
        for (int t = 0; t < TDN; ++t) a += s.attn[s.sel][t] * s.qkv[VP_OFF + t * OFC + tid];
        s.avsel[tid] = a;
    }
    __syncthreads();

    if (tid < OFC) {                    // selected row out-projection
        const float2* a  = (const float2*)&s.avsel[0];
        const float2* w2 = (const float2*)&s.owpad[tid][0];
        float a0 = 0.f;
        #pragma unroll 4
        for (int j = 0; j < 59; ++j) {
            float2 u = a[j], v = w2[j];
            a0 += u.x * v.x + u.y * v.y;
        }
        p.ws[(b ? WS_ATT_B : WS_ATT_A) + tid] = a0 + out_b[tid];
    }
    __threadfence();
}

// ---------------------------------------------------------------------------
// Phase 1b (blocks 12..15): branch prestage + eeg-side q/k/v sections.
// ---------------------------------------------------------------------------
__device__ void br_pre(int br, int tid, const Params& p, BrSm& s)
{
    for (int e = tid; e < 16 * OFC; e += 512) {
        int r = e / OFC, c = e - (e / OFC) * OFC;
        s.eeg_s[r][c] = p.x[(1 + r) * WL + (WL - OFC) + c];
    }
    for (int e = tid; e < 768; e += 512) {
        int q = e / 16, r = e % 16;
        s.w_inT[r][q] = p.cm_in_w[br * 768 + e];
    }
    if (tid < 48) s.b_in[tid] = p.cm_in_b[br * 48 + tid];
    if (tid >= 64 && tid < 320) {
        int e = tid - 64;
        s.w_out[e >> 4][e & 15] = p.cm_out_w[br * 256 + e];
    }
    if (tid >= 384 && tid < 400) s.b_out[tid - 384] = p.cm_out_b[br * 16 + (tid - 384)];
    for (int e = tid; e < COUT * 16 * KS; e += 512) s.cw[e] = p.conv_w[br * 1440 + e];
    if (tid >= 400 && tid < 400 + COUT) s.cb[tid - 400] = p.conv_b[br * COUT + (tid - 400)];
    {
        const float* pvg = (br < 2) ? p.projA_w : p.projB_w;
        if (tid >= 416 && tid < 432) s.pv[tid - 416] = pvg[tid - 416];
    }
    __syncthreads();

    if (tid < 48) {
        float a = 0.f;
        #pragma unroll
        for (int r = 0; r < 16; ++r) a += s.pv[r] * s.w_inT[r][tid];
        s.tv[tid / 16][tid % 16] = a;
    }
    __syncthreads();

    const bool d_r1 = (br == 0 || br == 3);
    for (int e = tid; e < 3 * OFC * 16; e += 512) {
        int sec = e / (OFC * 16);
        int rem = e - sec * OFC * 16;
        int j = rem >> 4, o = rem & 15;
        bool r1 = (sec == 0) ? d_r1 : !d_r1;
        if (!r1) {
            float a = 0.f;
            #pragma unroll
            for (int r = 0; r < 16; ++r) a += s.eeg_s[r][j] * s.w_inT[r][sec * 16 + o];
            a += s.b_in[sec * 16 + o];
            if (sec == 0) a *= 0.25f;
            float* dst = (sec == 0) ? &s.qpS[0][0] : (sec == 1 ? &s.kpS[0][0] : &s.vpS[0][0]);
            dst[j * 17 + o] = a;
        }
    }
}

// ---------------------------------------------------------------------------
// Phase 3 (blocks 12..15): rank-1 qkv, flash attention, out-proj, conv, max.
// ---------------------------------------------------------------------------
__device__ void br_main(int br, int tid, const Params& p, BrSm& s)
{
    const bool d_r1 = (br == 0 || br == 3);
    const float* ar = p.ws + ((br < 2) ? WS_ATT_A : WS_ATT_B);
    for (int j = tid; j < OFC; j += 512) s.arow[j] = ar[j];
    __syncthreads();

    for (int e = tid; e < 3 * OFC * 16; e += 512) {
        int sec = e / (OFC * 16);
        int rem = e - sec * OFC * 16;
        int j = rem >> 4, o = rem & 15;
        bool r1 = (sec == 0) ? d_r1 : !d_r1;
        if (r1) {
            float a = s.tv[sec][o] * s.arow[j] + s.b_in[sec * 16 + o];
            if (sec == 0) a *= 0.25f;
            float* dst = (sec == 0) ? &s.qpS[0][0] : (sec == 1 ? &s.kpS[0][0] : &s.vpS[0][0]);
            dst[j * 17 + o] = a;
        }
    }
    __syncthreads();

    const int g = tid >> 7, j = tid & 127;
    float q[16], acc[16];
    float m = -INFINITY, l = 0.f;
    #pragma unroll
    for (int r = 0; r < 16; ++r) acc[r] = 0.f;

    if (j < OFC) {
        #pragma unroll
        for (int r = 0; r < 16; ++r) q[r] = s.qpS[j][r];
        const int t0 = (g * OFC) >> 2, t1 = ((g + 1) * OFC) >> 2;
        for (int t = t0; t < t1; ++t) {
            const float* kr = &s.kpS[t][0];
            float sc = 0.f;
            #pragma unroll
            for (int r = 0; r < 16; ++r) sc += q[r] * kr[r];
            float mn = fmaxf(m, sc);
            float c  = __expf(m - mn);
            float pp = __expf(sc - mn);
            l = l * c + pp;
            const float* vr = &s.vpS[t][0];
            #pragma unroll
            for (int r = 0; r < 16; ++r) acc[r] = acc[r] * c + pp * vr[r];
            m = mn;
        }
        s.part_m[g][j] = m;
        s.part_l[g][j] = l;
        #pragma unroll
        for (int r = 0; r < 16; ++r) s.part_acc[g][j][r] = acc[r];
    }
    __syncthreads();

    if (tid < OFC) {
        float m0 = s.part_m[0][tid], m1 = s.part_m[1][tid];
        float m2 = s.part_m[2][tid], m3 = s.part_m[3][tid];
        float mm = fmaxf(fmaxf(m0, m1), fmaxf(m2, m3));
        float c0 = __expf(m0 - mm), c1 = __expf(m1 - mm);
        float c2 = __expf(m2 - mm), c3 = __expf(m3 - mm);
        float ll = c0 * s.part_l[0][tid] + c1 * s.part_l[1][tid]
                 + c2 * s.part_l[2][tid] + c3 * s.part_l[3][tid];
        float inv = 1.f / ll;
        float orow[16];
        #pragma unroll
        for (int r = 0; r < 16; ++r)
            orow[r] = (c0 * s.part_acc[0][tid][r] + c1 * s.part_acc[1][tid][r]
                     + c2 * s.part_acc[2][tid][r] + c3 * s.part_acc[3][tid][r]) * inv;
        for (int c = 0; c < 16; ++c) {
            float a = s.b_out[c];
            #pragma unroll
            for (int d = 0; d < 16; ++d) a += orow[d] * s.w_out[c][d];
            s.o2[tid][c] = a;
        }
    }
    __syncthreads();

    // conv: thread = (channel, 5-position group); 13-wide window in registers
    if (tid < COUT * 22) {
        int c = tid / 22, grp = tid - (tid / 22) * 22;
        int pbase = grp * 5;
        float acc5[5];
        #pragma unroll
        for (int i = 0; i < 5; ++i) acc5[i] = s.cb[c];
        for (int mI = 0; mI < 16; ++mI) {
            float win[13];
            #pragma unroll
            for (int t = 0; t < 13; ++t) win[t] = s.o2[pbase + t][mI];
            #pragma unroll
            for (int k = 0; k < KS; ++k) {
                float wv = s.cw[(c * 16 + mI) * KS + k];
                #pragma unroll
                for (int i = 0; i < 5; ++i) acc5[i] += win[i + k] * wv;
            }
        }
        float mx = fmaxf(fmaxf(fmaxf(acc5[0], acc5[1]), fmaxf(acc5[2], acc5[3])), acc5[4]);
        s.y[c][grp] = fmaxf(mx, 0.f);   // relu(max) == max(relu)
    }
    __syncthreads();

    if (tid < COUT) {
        float mx = s.y[tid][0];
        for (int g2 = 1; g2 < 22; ++g2) mx = fmaxf(mx, s.y[tid][g2]);
        p.ws[WS_FEATS + br * COUT + tid] = mx;
    }
    __threadfence();
}

// ---------------------------------------------------------------------------
__global__ __launch_bounds__(512) void fused_net(Params p)
{
    __shared__ Sm sm;
    cg::grid_group grid = cg::this_grid();
    const int blk = blockIdx.x;
    const int tid = threadIdx.x;

    // phase 1: td projections (0..11) || branch prestage (12..15)
    if (blk < NPBLK) td_proj(blk, tid, p, sm.t);
    else             br_pre(blk - NPBLK, tid, p, sm.b);
    grid.sync();

    // phase 2: attention + row-select (blocks 0,1)
    if (blk < 2) td_phase2(blk, tid, p, sm.t);
    grid.sync();

    // phase 3: branches (blocks 12..15)
    if (blk >= NPBLK) br_main(blk - NPBLK, tid, p, sm.b);
    grid.sync();

    // phase 4: head (block 0)
    if (blk == 0) {
        __syncthreads();
        if (tid < 40) sm.h.f[tid] = p.ws[WS_FEATS + tid];
        __syncthreads();
        if (tid < 40) {
            float a = p.fc1_b[tid];
            for (int k = 0; k < 40; ++k) a += sm.h.f[k] * p.fc1_w[tid * 40 + k];
            sm.h.h[tid] = 1.f / (1.f + __expf(-a));
        }
        __syncthreads();
        if (tid < 2) {
            float a = p.fc2_b[tid];
            for (int k = 0; k < 40; ++k) a += sm.h.h[k] * p.fc2_w[tid * 40 + k];
            p.out[tid] = 1.f / (1.f + __expf(-a));
        }
    }
}

// ---------------------------------------------------------------------------
extern "C" void kernel_launch(void* const* d_in, const int* in_sizes, int n_in,
                              void* d_out, int out_size, void* d_ws, size_t ws_size,
                              hipStream_t stream) {
    Params prm;
    prm.x         = (const float*)d_in[0];
    prm.tdA_in_w  = (const float*)d_in[1];
    prm.tdA_in_b  = (const float*)d_in[2];
    prm.tdA_out_w = (const float*)d_in[3];
    prm.tdA_out_b = (const float*)d_in[4];
    prm.tdB_in_w  = (const float*)d_in[5];
    prm.tdB_in_b  = (const float*)d_in[6];
    prm.tdB_out_w = (const float*)d_in[7];
    prm.tdB_out_b = (const float*)d_in[8];
    prm.cm_in_w   = (const float*)d_in[9];
    prm.cm_in_b   = (const float*)d_in[10];
    prm.cm_out_w  = (const float*)d_in[11];
    prm.cm_out_b  = (const float*)d_in[12];
    prm.projA_w   = (const float*)d_in[13];
    prm.projB_w   = (const float*)d_in[14];
    prm.conv_w    = (const float*)d_in[15];
    prm.conv_b    = (const float*)d_in[16];
    prm.fc1_w     = (const float*)d_in[17];
    prm.fc1_b     = (const float*)d_in[18];
    prm.fc2_w     = (const float*)d_in[19];
    prm.fc2_b     = (const float*)d_in[20];
    prm.ws        = (float*)d_ws;
    prm.out       = (float*)d_out;

    void* args[] = { &prm };
    hipLaunchCooperativeKernel((const void*)fused_net, dim3(16), dim3(512),
                               args, 0, stream);
}

// Round 6
// 67.505 us; speedup vs baseline: 2.4343x; 1.0846x over previous
//
#include <hip/hip_runtime.h>
#include <hip/hip_cooperative_groups.h>
#include <math.h>

#define WL   140
#define OFC  118
#define TDN  21
#define COUT 10
#define KS   9
#define IW_SZ (OFC * OFC)       // 13924

// ws layout (floats)
#define PROJ_STRIDE 6848
#define KP_OFF      1888
#define VP_OFF      4368
#define WS_ATT_A    13696
#define WS_ATT_B    13824
#define WS_FEATS    13952
#define WS_FLAGS    14080        // int flags from here (memset to 0 pre-launch)
// flag int indices (64B apart): 0=projA, 16=projB, 32=attA, 48=attB, 64=feats

struct Params {
    const float *x;
    const float *tdA_in_w, *tdA_in_b, *tdA_out_w, *tdA_out_b;
    const float *tdB_in_w, *tdB_in_b, *tdB_out_w, *tdB_out_b;
    const float *cm_in_w, *cm_in_b, *cm_out_w, *cm_out_b;
    const float *projA_w, *projB_w, *conv_w, *conv_b;
    const float *fc1_w, *fc1_b, *fc2_w, *fc2_b;
    float *ws, *out;
};

struct TdSm {                     // blocks 0..11 (proj); 0,1 also run phase 2
    float wpad[59][122];
    float inp[21][120];
    float owpad[OFC][122];
    float qkv[PROJ_STRIDE];
    float attn[16][22];
    float acs[22];
    float avcs[120];
    float colsum[120];
    float Ssum[16];
    float avsel[120];
    int   sel;
};

struct BrSm {                     // blocks 12..15
    float arow[120];
    float pv[16];
    float eeg_s[16][OFC];
    float w_inT[16][48];
    float b_in[48];
    float tv[3][16];
    float w_out[16][16];
    float b_out[16];
    float cw[COUT * 16 * KS];
    float cb[COUT];
    // br0/br3 (q rank-1):
    float kpS[OFC][17];
    float vpS[OFC][17];
    float u[120], v2[120];
    float part_m[4][128];
    float part_l[4][128];
    float part_acc[4][OFC][17];
    float o2[OFC][17];
    // br1/br2 (kv rank-1):
    float qpS[OFC][17];
    float a_[120], dvec[120];
    float Avec[16], Bvec[16];
    float Gc[COUT][KS], cb2[COUT];
    float y[COUT][22];
};

struct HdSm { float f[64]; float h[64]; };

union alignas(16) Sm { TdSm t; BrSm b; HdSm h; };

__device__ inline float wred(float v) {
    #pragma unroll
    for (int off = 32; off; off >>= 1) v += __shfl_xor(v, off);
    return v;
}

__device__ inline void waitflag(int* f, int target, int tid) {
    if (tid == 0) {
        while (__hip_atomic_load(f, __ATOMIC_ACQUIRE, __HIP_MEMORY_SCOPE_AGENT) < target)
            __builtin_amdgcn_s_sleep(1);
    }
    __syncthreads();
}

__device__ inline void postflag(int* f, int tid) {
    __syncthreads();
    __threadfence();
    if (tid == 0) __hip_atomic_fetch_add(f, 1, __ATOMIC_RELEASE, __HIP_MEMORY_SCOPE_AGENT);
}

// ---------------------------------------------------------------------------
// td projections: blk -> (side b, section, half). Stage 59x118 weight strip
// (stride-122 LDS) + inputs; thread-per-output dot; coalesced ws write.
// ---------------------------------------------------------------------------
__device__ void td_proj(int blk, int tid, const Params& p, TdSm& s)
{
    const int b    = blk / 6;
    const int rem  = blk % 6;
    const int sec  = rem >> 1;
    const int half = rem & 1;
    const float* in_w = (b ? p.tdB_in_w : p.tdA_in_w) + sec * IW_SZ + half * 59 * OFC;
    const float* in_b = (b ? p.tdB_in_b : p.tdA_in_b) + sec * OFC + half * 59;
    const float* wav  = p.x + (b ? 17 * WL : 0);

    for (int e = tid; e < 59 * 59; e += 512) {     // float2 staging
        int o = e / 59, j = e - o * 59;
        ((float2*)&s.wpad[o][0])[j] = ((const float2*)(in_w + o * OFC))[j];
    }
    if (sec == 0) {
        for (int e = tid; e < 16 * OFC; e += 512) {
            int r = e / OFC, c = e - (e / OFC) * OFC;
            s.inp[r][c] = p.x[(1 + r) * WL + (WL - OFC) + c];
        }
    } else {
        for (int e = tid; e < TDN * 120; e += 512) {
            int t = e / 120, j = e - (e / 120) * 120;
            s.inp[t][j] = wav[t + j];
        }
    }
    __syncthreads();

    const int   R     = (sec == 0) ? 16 : TDN;
    const float scale = (sec == 0) ? (1.0f / sqrtf(118.0f)) : 1.0f;
    float* dst = p.ws + b * PROJ_STRIDE
               + (sec == 0 ? 0 : (sec == 1 ? KP_OFF : VP_OFF));

    for (int e = tid; e < R * 59; e += 512) {
        int r = e / 59, o = e - r * 59;
        const float2* a  = (const float2*)&s.inp[r][0];
        const float2* w2 = (const float2*)&s.wpad[o][0];
        float s0 = 0.f;
        #pragma unroll 4
        for (int j = 0; j < 59; ++j) {
            float2 u = a[j], w = w2[j];
            s0 += u.x * w.x + u.y * w.y;
        }
        dst[r * OFC + half * 59 + o] = (s0 + in_b[o]) * scale;
    }
}

// ---------------------------------------------------------------------------
// phase 2 (blocks 0,1): scores + softmax + colsum row-select + selected row.
// ---------------------------------------------------------------------------
__device__ void td_phase2(int b, int tid, const Params& p, TdSm& s)
{
    const float* base  = p.ws + b * PROJ_STRIDE;
    const float* out_b = b ? p.tdB_out_b : p.tdA_out_b;
    const int wid = tid >> 6, lane = tid & 63;

    for (int e = tid; e < PROJ_STRIDE / 2; e += 512)
        ((float2*)s.qkv)[e] = ((const float2*)base)[e];
    __syncthreads();

    if (tid < 16 * TDN) {
        int i = tid / TDN, t = tid - (tid / TDN) * TDN;
        const float2* q = (const float2*)&s.qkv[i * OFC];
        const float2* k = (const float2*)&s.qkv[KP_OFF + t * OFC];
        float sc = 0.f;
        #pragma unroll 4
        for (int j = 0; j < 59; ++j) {
            float2 u = q[j], v = k[j];
            sc += u.x * v.x + u.y * v.y;
        }
        s.attn[i][t] = sc;
    }
    __syncthreads();

    if (tid < 16) {
        float m = s.attn[tid][0];
        for (int t = 1; t < TDN; ++t) m = fmaxf(m, s.attn[tid][t]);
        float l = 0.f;
        for (int t = 0; t < TDN; ++t) {
            float pp = __expf(s.attn[tid][t] - m);
            s.attn[tid][t] = pp;
            l += pp;
        }
        float inv = 1.f / l;
        for (int t = 0; t < TDN; ++t) s.attn[tid][t] *= inv;
    }
    __syncthreads();

    if (tid < TDN) {
        float a = 0.f;
        for (int i = 0; i < 16; ++i) a += s.attn[i][tid];
        s.acs[tid] = a;
    }
    __syncthreads();

    if (tid < OFC) {
        float a = 0.f;
        for (int t = 0; t < TDN; ++t) a += s.acs[t] * s.qkv[VP_OFF + t * OFC + tid];
        s.avcs[tid] = a;
    }
    __syncthreads();

    if (tid < OFC) {
        const float2* a  = (const float2*)&s.avcs[0];
        const float2* w2 = (const float2*)&s.owpad[tid][0];
        float a0 = 0.f;
        #pragma unroll 4
        for (int j = 0; j < 59; ++j) {
            float2 u = a[j], v = w2[j];
            a0 += u.x * v.x + u.y * v.y;
        }
        s.colsum[tid] = a0 + 16.f * out_b[tid];
    }
    __syncthreads();

    for (int d = wid; d < 16; d += 8) {
        const float* er = p.x + (1 + d) * WL + (WL - OFC);
        int j0 = lane * 2;
        float sc = 0.f;
        if (j0 < OFC) {
            float2 ev = *(const float2*)(er + j0);
            float2 cv = *(const float2*)(&s.colsum[j0]);
            sc = ev.x * cv.x + ev.y * cv.y;
        }
        sc = wred(sc);
        if (lane == 0) s.Ssum[d] = sc;
    }
    __syncthreads();

    if (tid == 0) {
        int best = 0; float bv = s.Ssum[0];
        for (int i = 1; i < 16; ++i)
            if (s.Ssum[i] > bv) { bv = s.Ssum[i]; best = i; }   // first-max
        s.sel = best;
    }
    __syncthreads();

    if (tid < OFC) {
        float a = 0.f;
        for (int t = 0; t < TDN; ++t) a += s.attn[s.sel][t] * s.qkv[VP_OFF + t * OFC + tid];
        s.avsel[tid] = a;
    }
    __syncthreads();

    if (tid < OFC) {
        const float2* a  = (const float2*)&s.avsel[0];
        const float2* w2 = (const float2*)&s.owpad[tid][0];
        float a0 = 0.f;
        #pragma unroll 4
        for (int j = 0; j < 59; ++j) {
            float2 u = a[j], v = w2[j];
            a0 += u.x * v.x + u.y * v.y;
        }
        p.ws[(b ? WS_ATT_B : WS_ATT_A) + tid] = a0 + out_b[tid];
    }
}

// ---------------------------------------------------------------------------
// branch prestage (blocks 12..15): everything that doesn't need arow.
// ---------------------------------------------------------------------------
__device__ void br_pre(int br, int tid, const Params& p, BrSm& s)
{
    const bool d_r1 = (br == 0 || br == 3);   // q side rank-1 (data = wA/wB)

    for (int e = tid; e < 16 * OFC; e += 512) {
        int r = e / OFC, c = e - (e / OFC) * OFC;
        s.eeg_s[r][c] = p.x[(1 + r) * WL + (WL - OFC) + c];
    }
    for (int e = tid; e < 768; e += 512) {
        int q = e / 16, r = e % 16;
        s.w_inT[r][q] = p.cm_in_w[br * 768 + e];
    }
    if (tid < 48) s.b_in[tid] = p.cm_in_b[br * 48 + tid];
    if (tid >= 64 && tid < 320) {
        int e = tid - 64;
        s.w_out[e >> 4][e & 15] = p.cm_out_w[br * 256 + e];
    }
    if (tid >= 384 && tid < 400) s.b_out[tid - 384] = p.cm_out_b[br * 16 + (tid - 384)];
    for (int e = tid; e < COUT * 16 * KS; e += 512) s.cw[e] = p.conv_w[br * 1440 + e];
    if (tid >= 400 && tid < 410) s.cb[tid - 400] = p.conv_b[br * COUT + (tid - 400)];
    {
        const float* pvg = (br < 2) ? p.projA_w : p.projB_w;
        if (tid >= 416 && tid < 432) s.pv[tid - 416] = pvg[tid - 416];
    }
    __syncthreads();

    if (tid < 48) {
        float a = 0.f;
        #pragma unroll
        for (int r = 0; r < 16; ++r) a += s.pv[r] * s.w_inT[r][tid];
        s.tv[tid / 16][tid % 16] = a;
    }
    __syncthreads();

    if (d_r1) {
        // k,v = eeg-projected (full); then u[t]=tvq.k[t], v2[t]=bq.k[t]
        for (int e = tid; e < 2 * OFC * 16; e += 512) {
            int sec01 = e / (OFC * 16);
            int rem = e - sec01 * OFC * 16;
            int j = rem >> 4, o = rem & 15;
            float a = 0.f;
            #pragma unroll
            for (int r = 0; r < 16; ++r) a += s.eeg_s[r][j] * s.w_inT[r][(1 + sec01) * 16 + o];
            a += s.b_in[(1 + sec01) * 16 + o];
            (sec01 ? &s.vpS[0][0] : &s.kpS[0][0])[j * 17 + o] = a;
        }
        __syncthreads();
        if (tid < OFC) {
            float uu = 0.f, vv = 0.f;
            #pragma unroll
            for (int o = 0; o < 16; ++o) {
                float kv = s.kpS[tid][o];
                uu += s.tv[0][o] * kv;
                vv += s.b_in[o] * kv;
            }
            s.u[tid] = uu; s.v2[tid] = vv;
        }
    } else {
        // q = eeg-projected (scaled); a[j] = qp[j].tvk; conv collapse precompute
        for (int e = tid; e < OFC * 16; e += 512) {
            int j = e >> 4, o = e & 15;
            float a = 0.f;
            #pragma unroll
            for (int r = 0; r < 16; ++r) a += s.eeg_s[r][j] * s.w_inT[r][o];
            s.qpS[j][o] = (a + s.b_in[o]) * 0.25f;
        }
        __syncthreads();
        if (tid < OFC) {
            float a = 0.f;
            #pragma unroll
            for (int o = 0; o < 16; ++o) a += s.qpS[tid][o] * s.tv[1][o];
            s.a_[tid] = a;
        }
        if (tid >= 128 && tid < 144) {
            int c = tid - 128;
            float A = 0.f, B = 0.f;
            #pragma unroll
            for (int o = 0; o < 16; ++o) {
                A += s.tv[2][o] * s.w_out[c][o];
                B += s.b_in[32 + o] * s.w_out[c][o];
            }
            s.Avec[c] = A;
            s.Bvec[c] = B + s.b_out[c];
        }
        __syncthreads();
        if (tid < COUT * KS) {
            int c = tid / KS, k = tid - (tid / KS) * KS;
            float g = 0.f;
            #pragma unroll
            for (int m = 0; m < 16; ++m) g += s.Avec[m] * s.cw[(c * 16 + m) * KS + k];
            s.Gc[c][k] = g;
        }
        if (tid >= 128 && tid < 128 + COUT) {
            int c = tid - 128;
            float cc = s.cb[c];
            #pragma unroll
            for (int m = 0; m < 16; ++m) {
                float bsum = 0.f;
                #pragma unroll
                for (int k = 0; k < KS; ++k) bsum += s.cw[(c * 16 + m) * KS + k];
                cc += s.Bvec[m] * bsum;
            }
            s.cb2[c] = cc;
        }
    }
}

// ---------------------------------------------------------------------------
// branch main (blocks 12..15), after arow is available.
// ---------------------------------------------------------------------------
__device__ void br_main(int br, int tid, const Params& p, BrSm& s)
{
    const bool d_r1 = (br == 0 || br == 3);
    const float* ar = p.ws + ((br < 2) ? WS_ATT_A : WS_ATT_B);
    if (tid < OFC) s.arow[tid] = ar[tid];
    __syncthreads();

    if (d_r1) {
        // flash attention, score = 0.25*(arow[j]*u[t] + v2[t]); PV over vpS
        const int g = tid >> 7, j = tid & 127;
        float acc[16];
        float m = -INFINITY, l = 0.f;
        #pragma unroll
        for (int r = 0; r < 16; ++r) acc[r] = 0.f;

        if (j < OFC) {
            const float aj = s.arow[j];
            const int t0 = (g * OFC) >> 2, t1 = ((g + 1) * OFC) >> 2;
            for (int t = t0; t < t1; ++t) {
                float sc = 0.25f * fmaf(aj, s.u[t], s.v2[t]);
                float mn = fmaxf(m, sc);
                float c  = __expf(m - mn);
                float pp = __expf(sc - mn);
                l = l * c + pp;
                const float* vr = &s.vpS[t][0];
                #pragma unroll
                for (int r = 0; r < 16; ++r) acc[r] = acc[r] * c + pp * vr[r];
                m = mn;
            }
            s.part_m[g][j] = m;
            s.part_l[g][j] = l;
            #pragma unroll
            for (int r = 0; r < 16; ++r) s.part_acc[g][j][r] = acc[r];
        }
        __syncthreads();

        if (tid < OFC) {
            float m0 = s.part_m[0][tid], m1 = s.part_m[1][tid];
            float m2 = s.part_m[2][tid], m3 = s.part_m[3][tid];
            float mm = fmaxf(fmaxf(m0, m1), fmaxf(m2, m3));
            float c0 = __expf(m0 - mm), c1 = __expf(m1 - mm);
            float c2 = __expf(m2 - mm), c3 = __expf(m3 - mm);
            float ll = c0 * s.part_l[0][tid] + c1 * s.part_l[1][tid]
                     + c2 * s.part_l[2][tid] + c3 * s.part_l[3][tid];
            float inv = 1.f / ll;
            float orow[16];
            #pragma unroll
            for (int r = 0; r < 16; ++r)
                orow[r] = (c0 * s.part_acc[0][tid][r] + c1 * s.part_acc[1][tid][r]
                         + c2 * s.part_acc[2][tid][r] + c3 * s.part_acc[3][tid][r]) * inv;
            for (int c = 0; c < 16; ++c) {
                float a = s.b_out[c];
                #pragma unroll
                for (int d = 0; d < 16; ++d) a += orow[d] * s.w_out[c][d];
                s.o2[tid][c] = a;
            }
        }
        __syncthreads();

        if (tid < COUT * 22) {
            int c = tid / 22, grp = tid - (tid / 22) * 22;
            int pbase = grp * 5;
            float acc5[5];
            #pragma unroll
            for (int i = 0; i < 5; ++i) acc5[i] = s.cb[c];
            for (int mI = 0; mI < 16; ++mI) {
                float win[13];
                #pragma unroll
                for (int t = 0; t < 13; ++t) win[t] = s.o2[pbase + t][mI];
                #pragma unroll
                for (int k = 0; k < KS; ++k) {
                    float wv = s.cw[(c * 16 + mI) * KS + k];
                    #pragma unroll
                    for (int i = 0; i < 5; ++i) acc5[i] += win[i + k] * wv;
                }
            }
            float mx = fmaxf(fmaxf(fmaxf(acc5[0], acc5[1]), fmaxf(acc5[2], acc5[3])), acc5[4]);
            s.y[c][grp] = fmaxf(mx, 0.f);
        }
        __syncthreads();
    } else {
        // kv rank-1: p = softmax_t(a[j]*arow[t]); d[j] = p . arow; collapsed conv
        if (tid < OFC) {
            const float aj = s.a_[tid];
            float m = -INFINITY;
            for (int t = 0; t < OFC; ++t) m = fmaxf(m, aj * s.arow[t]);
            float l = 0.f, d = 0.f;
            for (int t = 0; t < OFC; ++t) {
                float e = __expf(aj * s.arow[t] - m);
                l += e;
                d += e * s.arow[t];
            }
            s.dvec[tid] = d / l;
        }
        __syncthreads();

        if (tid < COUT * 22) {
            int c = tid / 22, grp = tid - (tid / 22) * 22;
            int pbase = grp * 5;
            float win[13];
            #pragma unroll
            for (int t = 0; t < 13; ++t) win[t] = s.dvec[pbase + t];
            float acc5[5];
            #pragma unroll
            for (int i = 0; i < 5; ++i) acc5[i] = s.cb2[c];
            #pragma unroll
            for (int k = 0; k < KS; ++k) {
                float wv = s.Gc[c][k];
                #pragma unroll
                for (int i = 0; i < 5; ++i) acc5[i] += win[i + k] * wv;
            }
            float mx = fmaxf(fmaxf(fmaxf(acc5[0], acc5[1]), fmaxf(acc5[2], acc5[3])), acc5[4]);
            s.y[c][grp] = fmaxf(mx, 0.f);
        }
        __syncthreads();
    }

    if (tid < COUT) {
        float mx = s.y[tid][0];
        for (int g2 = 1; g2 < 22; ++g2) mx = fmaxf(mx, s.y[tid][g2]);
        p.ws[WS_FEATS + br * COUT + tid] = mx;
    }
}

// ---------------------------------------------------------------------------
__global__ __launch_bounds__(512) void fused_net(Params p)
{
    __shared__ Sm sm;
    const int blk = blockIdx.x;
    const int tid = threadIdx.x;
    int* flags = (int*)(p.ws + WS_FLAGS);

    if (blk < 12) {
        td_proj(blk, tid, p, sm.t);
        postflag(&flags[(blk / 6) * 16], tid);          // projA / projB

        if (blk < 2) {
            // stage out_w while other proj blocks finish
            const float* ow = blk ? p.tdB_out_w : p.tdA_out_w;
            for (int e = tid; e < OFC * 59; e += 512) {
                int o = e / 59, j = e - o * 59;
                ((float2*)&sm.t.owpad[o][0])[j] = ((const float2*)(ow + o * OFC))[j];
            }
            waitflag(&flags[blk * 16], 6, tid);
            td_phase2(blk, tid, p, sm.t);
            postflag(&flags[32 + blk * 16], tid);       // attA / attB

            if (blk == 0) {
                waitflag(&flags[64], 4, tid);
                __syncthreads();
                if (tid < 40) sm.h.f[tid] = p.ws[WS_FEATS + tid];
                __syncthreads();
                if (tid < 40) {
                    float a = p.fc1_b[tid];
                    for (int k = 0; k < 40; ++k) a += sm.h.f[k] * p.fc1_w[tid * 40 + k];
                    sm.h.h[tid] = 1.f / (1.f + __expf(-a));
                }
                __syncthreads();
                if (tid < 2) {
                    float a = p.fc2_b[tid];
                    for (int k = 0; k < 40; ++k) a += sm.h.h[k] * p.fc2_w[tid * 40 + k];
                    p.out[tid] = 1.f / (1.f + __expf(-a));
                }
            }
        }
    } else {
        const int br = blk - 12;
        br_pre(br, tid, p, sm.b);
        waitflag(&flags[32 + ((br < 2) ? 0 : 16)], 1, tid);
        br_main(br, tid, p, sm.b);
        postflag(&flags[64], tid);
    }
}

// ---------------------------------------------------------------------------
extern "C" void kernel_launch(void* const* d_in, const int* in_sizes, int n_in,
                              void* d_out, int out_size, void* d_ws, size_t ws_size,
                              hipStream_t stream) {
    Params prm;
    prm.x         = (const float*)d_in[0];
    prm.tdA_in_w  = (const float*)d_in[1];
    prm.tdA_in_b  = (const float*)d_in[2];
    prm.tdA_out_w = (const float*)d_in[3];
    prm.tdA_out_b = (const float*)d_in[4];
    prm.tdB_in_w  = (const float*)d_in[5];
    prm.tdB_in_b  = (const float*)d_in[6];
    prm.tdB_out_w = (const float*)d_in[7];
    prm.tdB_out_b = (const float*)d_in[8];
    prm.cm_in_w   = (const float*)d_in[9];
    prm.cm_in_b   = (const float*)d_in[10];
    prm.cm_out_w  = (const float*)d_in[11];
    prm.cm_out_b  = (const float*)d_in[12];
    prm.projA_w   = (const float*)d_in[13];
    prm.projB_w   = (const float*)d_in[14];
    prm.conv_w    = (const float*)d_in[15];
    prm.conv_b    = (const float*)d_in[16];
    prm.fc1_w     = (const float*)d_in[17];
    prm.fc1_b     = (const float*)d_in[18];
    prm.fc2_w     = (const float*)d_in[19];
    prm.fc2_b     = (const float*)d_in[20];
    prm.ws        = (float*)d_ws;
    prm.out       = (float*)d_out;

    // zero the sync flags (captured as a memset node; runs before the kernel
    // on every replay — makes the flag protocol deterministic)
    hipMemsetAsync((char*)d_ws + WS_FLAGS * sizeof(float), 0, 512, stream);

    void* args[] = { &prm };
    hipLaunchCooperativeKernel((const void*)fused_net, dim3(16), dim3(512),
                               args, 0, stream);
}

// Round 7
// 63.354 us; speedup vs baseline: 2.5938x; 1.0655x over previous
//
#include <hip/hip_runtime.h>
#include <math.h>

#define WL   140
#define OFC  118
#define TDN  21
#define COUT 10
#define KS   9
#define IW_SZ (OFC * OFC)       // 13924

// ws layout (floats)
#define PROJ_STRIDE 6848
#define KP_OFF      1888
#define VP_OFF      4368
#define WS_ATT_A    13696
#define WS_ATT_B    13824
#define WS_FEATS    13952
#define WS_FLAGS    14080        // int flags from here (memset to 0 pre-launch)
// flag int indices (64B apart): 0=projA, 16=projB, 32=attA, 48=attB, 64=feats

struct Params {
    const float *x;
    const float *tdA_in_w, *tdA_in_b, *tdA_out_w, *tdA_out_b;
    const float *tdB_in_w, *tdB_in_b, *tdB_out_w, *tdB_out_b;
    const float *cm_in_w, *cm_in_b, *cm_out_w, *cm_out_b;
    const float *projA_w, *projB_w, *conv_w, *conv_b;
    const float *fc1_w, *fc1_b, *fc2_w, *fc2_b;
    float *ws, *out;
};

struct TdSm {                     // blocks 0..11 (proj); 0,1 also run phase 2
    float wpad[59][122];
    float inp[21][120];
    float owpad[OFC][122];
    float qpp[16][122];           // phase 2 staged, padded stride 122
    float kpp[TDN][122];
    float vpp[TDN][122];
    float attn[16][22];
    float acs[22];
    float avcs[120];
    float colsum[120];
    float Ssum[16];
    float avsel[120];
    int   sel;
};

struct BrSm {                     // blocks 12..15
    float arow[120];
    float pv[16];
    float eeg_s[16][OFC];
    float w_inT[16][48];
    float b_in[48];
    float tv[3][16];
    float w_out[16][16];
    float b_out[16];
    float cw[COUT * 16 * KS];
    float cb[COUT];
    // br0/br3 (q rank-1):
    float kpS[OFC][17];
    float vpS[OFC][17];
    float u[120], v2[120];
    float part_m[4][128];
    float part_l[4][128];
    float part_acc[4][OFC][17];
    float o2[OFC][17];
    // br1/br2 (kv rank-1):
    float qpS[OFC][17];
    float a_[120], dvec[120];
    float Avec[16], Bvec[16];
    float Gc[COUT][KS], cb2[COUT];
    float y[COUT][22];
};

struct HdSm { float f[64]; float h[64]; };

union alignas(16) Sm { TdSm t; BrSm b; HdSm h; };

__device__ inline float wred(float v) {
    #pragma unroll
    for (int off = 32; off; off >>= 1) v += __shfl_xor(v, off);
    return v;
}

// relaxed spin; ONE acquire fence after the condition is met
__device__ inline void waitflag(int* f, int target, int tid) {
    if (tid == 0) {
        while (__hip_atomic_load(f, __ATOMIC_RELAXED, __HIP_MEMORY_SCOPE_AGENT) < target)
            __builtin_amdgcn_s_sleep(1);
        __builtin_amdgcn_fence(__ATOMIC_ACQUIRE, "agent");
    }
    __syncthreads();
}

// barrier (drains each wave's stores) + single RELEASE RMW (does the L2 wb)
__device__ inline void postflag(int* f, int tid) {
    __syncthreads();
    if (tid == 0) __hip_atomic_fetch_add(f, 1, __ATOMIC_RELEASE, __HIP_MEMORY_SCOPE_AGENT);
}

// ---------------------------------------------------------------------------
// td projections: blk -> (side b, section, half). Stage 59x118 weight strip
// (stride-122 LDS) + inputs; thread-per-output dot; coalesced ws write.
// ---------------------------------------------------------------------------
__device__ void td_proj(int blk, int tid, const Params& p, TdSm& s)
{
    const int b    = blk / 6;
    const int rem  = blk % 6;
    const int sec  = rem >> 1;
    const int half = rem & 1;
    const float* in_w = (b ? p.tdB_in_w : p.tdA_in_w) + sec * IW_SZ + half * 59 * OFC;
    const float* in_b = (b ? p.tdB_in_b : p.tdA_in_b) + sec * OFC + half * 59;
    const float* wav  = p.x + (b ? 17 * WL : 0);

    for (int e = tid; e < 59 * 59; e += 512) {     // float2 staging
        int o = e / 59, j = e - o * 59;
        ((float2*)&s.wpad[o][0])[j] = ((const float2*)(in_w + o * OFC))[j];
    }
    if (sec == 0) {
        for (int e = tid; e < 16 * OFC; e += 512) {
            int r = e / OFC, c = e - (e / OFC) * OFC;
            s.inp[r][c] = p.x[(1 + r) * WL + (WL - OFC) + c];
        }
    } else {
        for (int e = tid; e < TDN * 120; e += 512) {
            int t = e / 120, j = e - (e / 120) * 120;
            s.inp[t][j] = wav[t + j];
        }
    }
    __syncthreads();

    const int   R     = (sec == 0) ? 16 : TDN;
    const float scale = (sec == 0) ? (1.0f / sqrtf(118.0f)) : 1.0f;
    float* dst = p.ws + b * PROJ_STRIDE
               + (sec == 0 ? 0 : (sec == 1 ? KP_OFF : VP_OFF));

    for (int e = tid; e < R * 59; e += 512) {
        int r = e / 59, o = e - r * 59;
        const float2* a  = (const float2*)&s.inp[r][0];
        const float2* w2 = (const float2*)&s.wpad[o][0];
        float s0 = 0.f;
        #pragma unroll 4
        for (int j = 0; j < 59; ++j) {
            float2 u = a[j], w = w2[j];
            s0 += u.x * w.x + u.y * w.y;
        }
        dst[r * OFC + half * 59 + o] = (s0 + in_b[o]) * scale;
    }
}

// ---------------------------------------------------------------------------
// phase 2 (blocks 0,1): scores + softmax + colsum row-select + selected row.
// ---------------------------------------------------------------------------
__device__ void td_phase2(int b, int tid, const Params& p, TdSm& s)
{
    const float* base  = p.ws + b * PROJ_STRIDE;
    const float* out_b = b ? p.tdB_out_b : p.tdA_out_b;
    const int wid = tid >> 6, lane = tid & 63;

    // stage q/k/v into padded rows (stride 122)
    for (int e = tid; e < 16 * 59; e += 512) {
        int r = e / 59, j = e - r * 59;
        ((float2*)&s.qpp[r][0])[j] = ((const float2*)(base + r * OFC))[j];
    }
    for (int e = tid; e < TDN * 59; e += 512) {
        int t = e / 59, j = e - t * 59;
        ((float2*)&s.kpp[t][0])[j] = ((const float2*)(base + KP_OFF + t * OFC))[j];
        ((float2*)&s.vpp[t][0])[j] = ((const float2*)(base + VP_OFF + t * OFC))[j];
    }
    __syncthreads();

    if (tid < 16 * TDN) {
        int i = tid / TDN, t = tid - (tid / TDN) * TDN;
        const float2* q = (const float2*)&s.qpp[i][0];
        const float2* k = (const float2*)&s.kpp[t][0];
        float sc = 0.f;
        #pragma unroll 4
        for (int j = 0; j < 59; ++j) {
            float2 u = q[j], v = k[j];
            sc += u.x * v.x + u.y * v.y;
        }
        s.attn[i][t] = sc;
    }
    __syncthreads();

    if (tid < 16) {
        float m = s.attn[tid][0];
        for (int t = 1; t < TDN; ++t) m = fmaxf(m, s.attn[tid][t]);
        float l = 0.f;
        for (int t = 0; t < TDN; ++t) {
            float pp = __expf(s.attn[tid][t] - m);
            s.attn[tid][t] = pp;
            l += pp;
        }
        float inv = 1.f / l;
        for (int t = 0; t < TDN; ++t) s.attn[tid][t] *= inv;
    }
    __syncthreads();

    if (tid < TDN) {
        float a = 0.f;
        for (int i = 0; i < 16; ++i) a += s.attn[i][tid];
        s.acs[tid] = a;
    }
    __syncthreads();

    if (tid < OFC) {
        float a = 0.f;
        for (int t = 0; t < TDN; ++t) a += s.acs[t] * s.vpp[t][tid];
        s.avcs[tid] = a;
    }
    __syncthreads();

    if (tid < OFC) {
        const float2* a  = (const float2*)&s.avcs[0];
        const float2* w2 = (const float2*)&s.owpad[tid][0];
        float a0 = 0.f;
        #pragma unroll 4
        for (int j = 0; j < 59; ++j) {
            float2 u = a[j], v = w2[j];
            a0 += u.x * v.x + u.y * v.y;
        }
        s.colsum[tid] = a0 + 16.f * out_b[tid];
    }
    __syncthreads();

    for (int d = wid; d < 16; d += 8) {
        const float* er = p.x + (1 + d) * WL + (WL - OFC);
        int j0 = lane * 2;
        float sc = 0.f;
        if (j0 < OFC) {
            float2 ev = *(const float2*)(er + j0);
            float2 cv = *(const float2*)(&s.colsum[j0]);
            sc = ev.x * cv.x + ev.y * cv.y;
        }
        sc = wred(sc);
        if (lane == 0) s.Ssum[d] = sc;
    }
    __syncthreads();

    if (tid == 0) {
        int best = 0; float bv = s.Ssum[0];
        for (int i = 1; i < 16; ++i)
            if (s.Ssum[i] > bv) { bv = s.Ssum[i]; best = i; }   // first-max
        s.sel = best;
    }
    __syncthreads();

    if (tid < OFC) {
        float a = 0.f;
        for (int t = 0; t < TDN; ++t) a += s.attn[s.sel][t] * s.vpp[t][tid];
        s.avsel[tid] = a;
    }
    __syncthreads();

    if (tid < OFC) {
        const float2* a  = (const float2*)&s.avsel[0];
        const float2* w2 = (const float2*)&s.owpad[tid][0];
        float a0 = 0.f;
        #pragma unroll 4
        for (int j = 0; j < 59; ++j) {
            float2 u = a[j], v = w2[j];
            a0 += u.x * v.x + u.y * v.y;
        }
        p.ws[(b ? WS_ATT_B : WS_ATT_A) + tid] = a0 + out_b[tid];
    }
}

// ---------------------------------------------------------------------------
// branch prestage (blocks 12..15): everything that doesn't need arow.
// ---------------------------------------------------------------------------
__device__ void br_pre(int br, int tid, const Params& p, BrSm& s)
{
    const bool d_r1 = (br == 0 || br == 3);   // q side rank-1 (data = wA/wB)

    for (int e = tid; e < 16 * OFC; e += 512) {
        int r = e / OFC, c = e - (e / OFC) * OFC;
        s.eeg_s[r][c] = p.x[(1 + r) * WL + (WL - OFC) + c];
    }
    for (int e = tid; e < 768; e += 512) {
        int q = e / 16, r = e % 16;
        s.w_inT[r][q] = p.cm_in_w[br * 768 + e];
    }
    if (tid < 48) s.b_in[tid] = p.cm_in_b[br * 48 + tid];
    if (tid >= 64 && tid < 320) {
        int e = tid - 64;
        s.w_out[e >> 4][e & 15] = p.cm_out_w[br * 256 + e];
    }
    if (tid >= 384 && tid < 400) s.b_out[tid - 384] = p.cm_out_b[br * 16 + (tid - 384)];
    for (int e = tid; e < COUT * 16 * KS; e += 512) s.cw[e] = p.conv_w[br * 1440 + e];
    if (tid >= 400 && tid < 410) s.cb[tid - 400] = p.conv_b[br * COUT + (tid - 400)];
    {
        const float* pvg = (br < 2) ? p.projA_w : p.projB_w;
        if (tid >= 416 && tid < 432) s.pv[tid - 416] = pvg[tid - 416];
    }
    __syncthreads();

    if (tid < 48) {
        float a = 0.f;
        #pragma unroll
        for (int r = 0; r < 16; ++r) a += s.pv[r] * s.w_inT[r][tid];
        s.tv[tid / 16][tid % 16] = a;
    }
    __syncthreads();

    if (d_r1) {
        for (int e = tid; e < 2 * OFC * 16; e += 512) {
            int sec01 = e / (OFC * 16);
            int rem = e - sec01 * OFC * 16;
            int j = rem >> 4, o = rem & 15;
            float a = 0.f;
            #pragma unroll
            for (int r = 0; r < 16; ++r) a += s.eeg_s[r][j] * s.w_inT[r][(1 + sec01) * 16 + o];
            a += s.b_in[(1 + sec01) * 16 + o];
            (sec01 ? &s.vpS[0][0] : &s.kpS[0][0])[j * 17 + o] = a;
        }
        __syncthreads();
        if (tid < OFC) {
            float uu = 0.f, vv = 0.f;
            #pragma unroll
            for (int o = 0; o < 16; ++o) {
                float kv = s.kpS[tid][o];
                uu += s.tv[0][o] * kv;
                vv += s.b_in[o] * kv;
            }
            s.u[tid] = uu; s.v2[tid] = vv;
        }
    } else {
        for (int e = tid; e < OFC * 16; e += 512) {
            int j = e >> 4, o = e & 15;
            float a = 0.f;
            #pragma unroll
            for (int r = 0; r < 16; ++r) a += s.eeg_s[r][j] * s.w_inT[r][o];
            s.qpS[j][o] = (a + s.b_in[o]) * 0.25f;
        }
        __syncthreads();
        if (tid < OFC) {
            float a = 0.f;
            #pragma unroll
            for (int o = 0; o < 16; ++o) a += s.qpS[tid][o] * s.tv[1][o];
            s.a_[tid] = a;
        }
        if (tid >= 128 && tid < 144) {
            int c = tid - 128;
            float A = 0.f, B = 0.f;
            #pragma unroll
            for (int o = 0; o < 16; ++o) {
                A += s.tv[2][o] * s.w_out[c][o];
                B += s.b_in[32 + o] * s.w_out[c][o];
            }
            s.Avec[c] = A;
            s.Bvec[c] = B + s.b_out[c];
        }
        __syncthreads();
        if (tid < COUT * KS) {
            int c = tid / KS, k = tid - (tid / KS) * KS;
            float g = 0.f;
            #pragma unroll
            for (int m = 0; m < 16; ++m) g += s.Avec[m] * s.cw[(c * 16 + m) * KS + k];
            s.Gc[c][k] = g;
        }
        if (tid >= 128 && tid < 128 + COUT) {
            int c = tid - 128;
            float cc = s.cb[c];
            #pragma unroll
            for (int m = 0; m < 16; ++m) {
                float bsum = 0.f;
                #pragma unroll
                for (int k = 0; k < KS; ++k) bsum += s.cw[(c * 16 + m) * KS + k];
                cc += s.Bvec[m] * bsum;
            }
            s.cb2[c] = cc;
        }
    }
}

// ---------------------------------------------------------------------------
// branch main (blocks 12..15), after arow is available.
// ---------------------------------------------------------------------------
__device__ void br_main(int br, int tid, const Params& p, BrSm& s)
{
    const bool d_r1 = (br == 0 || br == 3);
    const float* ar = p.ws + ((br < 2) ? WS_ATT_A : WS_ATT_B);
    if (tid < OFC) s.arow[tid] = ar[tid];
    __syncthreads();

    if (d_r1) {
        const int g = tid >> 7, j = tid & 127;
        float acc[16];
        float m = -INFINITY, l = 0.f;
        #pragma unroll
        for (int r = 0; r < 16; ++r) acc[r] = 0.f;

        if (j < OFC) {
            const float aj = s.arow[j];
            const int t0 = (g * OFC) >> 2, t1 = ((g + 1) * OFC) >> 2;
            for (int t = t0; t < t1; ++t) {
                float sc = 0.25f * fmaf(aj, s.u[t], s.v2[t]);
                float mn = fmaxf(m, sc);
                float c  = __expf(m - mn);
                float pp = __expf(sc - mn);
                l = l * c + pp;
                const float* vr = &s.vpS[t][0];
                #pragma unroll
                for (int r = 0; r < 16; ++r) acc[r] = acc[r] * c + pp * vr[r];
                m = mn;
            }
            s.part_m[g][j] = m;
            s.part_l[g][j] = l;
            #pragma unroll
            for (int r = 0; r < 16; ++r) s.part_acc[g][j][r] = acc[r];
        }
        __syncthreads();

        if (tid < OFC) {
            float m0 = s.part_m[0][tid], m1 = s.part_m[1][tid];
            float m2 = s.part_m[2][tid], m3 = s.part_m[3][tid];
            float mm = fmaxf(fmaxf(m0, m1), fmaxf(m2, m3));
            float c0 = __expf(m0 - mm), c1 = __expf(m1 - mm);
            float c2 = __expf(m2 - mm), c3 = __expf(m3 - mm);
            float ll = c0 * s.part_l[0][tid] + c1 * s.part_l[1][tid]
                     + c2 * s.part_l[2][tid] + c3 * s.part_l[3][tid];
            float inv = 1.f / ll;
            float orow[16];
            #pragma unroll
            for (int r = 0; r < 16; ++r)
                orow[r] = (c0 * s.part_acc[0][tid][r] + c1 * s.part_acc[1][tid][r]
                         + c2 * s.part_acc[2][tid][r] + c3 * s.part_acc[3][tid][r]) * inv;
            for (int c = 0; c < 16; ++c) {
                float a = s.b_out[c];
                #pragma unroll
                for (int d = 0; d < 16; ++d) a += orow[d] * s.w_out[c][d];
                s.o2[tid][c] = a;
            }
        }
        __syncthreads();

        if (tid < COUT * 22) {
            int c = tid / 22, grp = tid - (tid / 22) * 22;
            int pbase = grp * 5;
            float acc5[5];
            #pragma unroll
            for (int i = 0; i < 5; ++i) acc5[i] = s.cb[c];
            for (int mI = 0; mI < 16; ++mI) {
                float win[13];
                #pragma unroll
                for (int t = 0; t < 13; ++t) win[t] = s.o2[pbase + t][mI];
                #pragma unroll
                for (int k = 0; k < KS; ++k) {
                    float wv = s.cw[(c * 16 + mI) * KS + k];
                    #pragma unroll
                    for (int i = 0; i < 5; ++i) acc5[i] += win[i + k] * wv;
                }
            }
            float mx = fmaxf(fmaxf(fmaxf(acc5[0], acc5[1]), fmaxf(acc5[2], acc5[3])), acc5[4]);
            s.y[c][grp] = fmaxf(mx, 0.f);
        }
        __syncthreads();
    } else {
        if (tid < OFC) {
            const float aj = s.a_[tid];
            float m = -INFINITY;
            for (int t = 0; t < OFC; ++t) m = fmaxf(m, aj * s.arow[t]);
            float l = 0.f, d = 0.f;
            for (int t = 0; t < OFC; ++t) {
                float e = __expf(aj * s.arow[t] - m);
                l += e;
                d += e * s.arow[t];
            }
            s.dvec[tid] = d / l;
        }
        __syncthreads();

        if (tid < COUT * 22) {
            int c = tid / 22, grp = tid - (tid / 22) * 22;
            int pbase = grp * 5;
            float win[13];
            #pragma unroll
            for (int t = 0; t < 13; ++t) win[t] = s.dvec[pbase + t];
            float acc5[5];
            #pragma unroll
            for (int i = 0; i < 5; ++i) acc5[i] = s.cb2[c];
            #pragma unroll
            for (int k = 0; k < KS; ++k) {
                float wv = s.Gc[c][k];
                #pragma unroll
                for (int i = 0; i < 5; ++i) acc5[i] += win[i + k] * wv;
            }
            float mx = fmaxf(fmaxf(fmaxf(acc5[0], acc5[1]), fmaxf(acc5[2], acc5[3])), acc5[4]);
            s.y[c][grp] = fmaxf(mx, 0.f);
        }
        __syncthreads();
    }

    if (tid < COUT) {
        float mx = s.y[tid][0];
        for (int g2 = 1; g2 < 22; ++g2) mx = fmaxf(mx, s.y[tid][g2]);
        p.ws[WS_FEATS + br * COUT + tid] = mx;
    }
}

// ---------------------------------------------------------------------------
__global__ __launch_bounds__(512) void fused_net(Params p)
{
    __shared__ Sm sm;
    const int blk = blockIdx.x;
    const int tid = threadIdx.x;
    int* flags = (int*)(p.ws + WS_FLAGS);

    if (blk < 12) {
        td_proj(blk, tid, p, sm.t);
        postflag(&flags[(blk / 6) * 16], tid);          // projA / projB

        if (blk < 2) {
            // stage out_w while other proj blocks finish
            const float* ow = blk ? p.tdB_out_w : p.tdA_out_w;
            for (int e = tid; e < OFC * 59; e += 512) {
                int o = e / 59, j = e - o * 59;
                ((float2*)&sm.t.owpad[o][0])[j] = ((const float2*)(ow + o * OFC))[j];
            }
            waitflag(&flags[blk * 16], 6, tid);
            td_phase2(blk, tid, p, sm.t);
            postflag(&flags[32 + blk * 16], tid);       // attA / attB

            if (blk == 0) {
                waitflag(&flags[64], 4, tid);
                __syncthreads();
                if (tid < 40) sm.h.f[tid] = p.ws[WS_FEATS + tid];
                __syncthreads();
                if (tid < 40) {
                    float a = p.fc1_b[tid];
                    for (int k = 0; k < 40; ++k) a += sm.h.f[k] * p.fc1_w[tid * 40 + k];
                    sm.h.h[tid] = 1.f / (1.f + __expf(-a));
                }
                __syncthreads();
                if (tid < 2) {
                    float a = p.fc2_b[tid];
                    for (int k = 0; k < 40; ++k) a += sm.h.h[k] * p.fc2_w[tid * 40 + k];
                    p.out[tid] = 1.f / (1.f + __expf(-a));
                }
            }
        }
    } else {
        const int br = blk - 12;
        br_pre(br, tid, p, sm.b);
        waitflag(&flags[32 + ((br < 2) ? 0 : 16)], 1, tid);
        br_main(br, tid, p, sm.b);
        postflag(&flags[64], tid);
    }
}

// ---------------------------------------------------------------------------
extern "C" void kernel_launch(void* const* d_in, const int* in_sizes, int n_in,
                              void* d_out, int out_size, void* d_ws, size_t ws_size,
                              hipStream_t stream) {
    Params prm;
    prm.x         = (const float*)d_in[0];
    prm.tdA_in_w  = (const float*)d_in[1];
    prm.tdA_in_b  = (const float*)d_in[2];
    prm.tdA_out_w = (const float*)d_in[3];
    prm.tdA_out_b = (const float*)d_in[4];
    prm.tdB_in_w  = (const float*)d_in[5];
    prm.tdB_in_b  = (const float*)d_in[6];
    prm.tdB_out_w = (const float*)d_in[7];
    prm.tdB_out_b = (const float*)d_in[8];
    prm.cm_in_w   = (const float*)d_in[9];
    prm.cm_in_b   = (const float*)d_in[10];
    prm.cm_out_w  = (const float*)d_in[11];
    prm.cm_out_b  = (const float*)d_in[12];
    prm.projA_w   = (const float*)d_in[13];
    prm.projB_w   = (const float*)d_in[14];
    prm.conv_w    = (const float*)d_in[15];
    prm.conv_b    = (const float*)d_in[16];
    prm.fc1_w     = (const float*)d_in[17];
    prm.fc1_b     = (const float*)d_in[18];
    prm.fc2_w     = (const float*)d_in[19];
    prm.fc2_b     = (const float*)d_in[20];
    prm.ws        = (float*)d_ws;
    prm.out       = (float*)d_out;

    // zero the sync flags (captured memset node; runs before the kernel on
    // every replay — makes the flag protocol deterministic)
    hipMemsetAsync((char*)d_ws + WS_FLAGS * sizeof(float), 0, 512, stream);

    void* args[] = { &prm };
    hipLaunchCooperativeKernel((const void*)fused_net, dim3(16), dim3(512),
                               args, 0, stream);
}

// Round 8
// 38.675 us; speedup vs baseline: 4.2489x; 1.6381x over previous
//
#include <hip/hip_runtime.h>
#include <math.h>

#define WL   140
#define OFC  118
#define TDN  21
#define COUT 10
#define KS   9
#define IW_SZ (OFC * OFC)       // 13924

// ws layout (floats)
#define PROJ_STRIDE 6848
#define KP_OFF      1888
#define VP_OFF      4368
#define WS_ATT_A    13696
#define WS_ATT_B    13824
#define WS_FEATS    13952
#define WS_FLAGS    14080        // int slots from here (self-resetting protocol)

// flag slots (stride 16 ints): proj side b, producer k -> slot b*6+k (0..11);
// attA=12, attB=13, feats br -> 14+br (14..17). 18 slots total.
#define MAGIC 0x1F2E3D4C
#define NSLOTS 18

struct Params {
    const float *x;
    const float *tdA_in_w, *tdA_in_b, *tdA_out_w, *tdA_out_b;
    const float *tdB_in_w, *tdB_in_b, *tdB_out_w, *tdB_out_b;
    const float *cm_in_w, *cm_in_b, *cm_out_w, *cm_out_b;
    const float *projA_w, *projB_w, *conv_w, *conv_b;
    const float *fc1_w, *fc1_b, *fc2_w, *fc2_b;
    float *ws, *out;
};

struct TdSm {                     // blocks 0..11 (proj); 0,1 also run phase 2
    float wpad[59][122];
    float inp[21][120];
    float owpad[OFC][122];
    float qpp[16][122];
    float kpp[TDN][122];
    float vpp[TDN][122];
    float attn[16][22];
    float acs[22];
    float avcs[120];
    float colsum[120];
    float Ssum[16];
    float avsel[120];
    int   sel;
};

struct BrSm {                     // blocks 12..15
    float arow[120];
    float pv[16];
    float eeg_s[16][OFC];
    float w_inT[16][48];
    float b_in[48];
    float tv[3][16];
    float w_out[16][16];
    float b_out[16];
    float cw[COUT * 16 * KS];
    float cb[COUT];
    // br0/br3 (q rank-1):
    float kpS[OFC][17];
    float vpS[OFC][17];
    float u[120], v2[120];
    float part_m[4][128];
    float part_l[4][128];
    float part_acc[4][OFC][17];
    float o2[OFC][17];
    // br1/br2 (kv rank-1):
    float qpS[OFC][17];
    float a_[120], dvec[120];
    float Avec[16], Bvec[16];
    float Gc[COUT][KS], cb2[COUT];
    float y[COUT][22];
};

struct HdSm { float f[64]; float h[64]; };

union alignas(16) Sm { TdSm t; BrSm b; HdSm h; };

__device__ inline float wred(float v) {
    #pragma unroll
    for (int off = 32; off; off >>= 1) v += __shfl_xor(v, off);
    return v;
}

// producer: barrier (all block stores done) + single RELEASE store of MAGIC
__device__ inline void postM(int* f, int tid) {
    __syncthreads();
    if (tid == 0)
        __hip_atomic_store(f, MAGIC, __ATOMIC_RELEASE, __HIP_MEMORY_SCOPE_AGENT);
}

// consumer: relaxed spin on n slots; ONE acquire fence when all are MAGIC
__device__ inline void waitM(int* base, int first, int n, int tid) {
    if (tid == 0) {
        for (int i = 0; i < n; ++i) {
            int* f = base + (first + i) * 16;
            while (__hip_atomic_load(f, __ATOMIC_RELAXED, __HIP_MEMORY_SCOPE_AGENT) != MAGIC)
                __builtin_amdgcn_s_sleep(1);
        }
        __builtin_amdgcn_fence(__ATOMIC_ACQUIRE, "agent");
    }
    __syncthreads();
}

// ---------------------------------------------------------------------------
// td projections: blk -> (side b, section, half). Stage 59x118 weight strip
// (stride-122 LDS) + inputs; thread-per-output dot; coalesced ws write.
// ---------------------------------------------------------------------------
__device__ void td_proj(int blk, int tid, const Params& p, TdSm& s)
{
    const int b    = blk / 6;
    const int rem  = blk % 6;
    const int sec  = rem >> 1;
    const int half = rem & 1;
    const float* in_w = (b ? p.tdB_in_w : p.tdA_in_w) + sec * IW_SZ + half * 59 * OFC;
    const float* in_b = (b ? p.tdB_in_b : p.tdA_in_b) + sec * OFC + half * 59;
    const float* wav  = p.x + (b ? 17 * WL : 0);

    for (int e = tid; e < 59 * 59; e += 512) {     // float2 staging
        int o = e / 59, j = e - o * 59;
        ((float2*)&s.wpad[o][0])[j] = ((const float2*)(in_w + o * OFC))[j];
    }
    if (sec == 0) {
        for (int e = tid; e < 16 * OFC; e += 512) {
            int r = e / OFC, c = e - (e / OFC) * OFC;
            s.inp[r][c] = p.x[(1 + r) * WL + (WL - OFC) + c];
        }
    } else {
        for (int e = tid; e < TDN * 120; e += 512) {
            int t = e / 120, j = e - (e / 120) * 120;
            s.inp[t][j] = wav[t + j];
        }
    }
    __syncthreads();

    const int   R     = (sec == 0) ? 16 : TDN;
    const float scale = (sec == 0) ? (1.0f / sqrtf(118.0f)) : 1.0f;
    float* dst = p.ws + b * PROJ_STRIDE
               + (sec == 0 ? 0 : (sec == 1 ? KP_OFF : VP_OFF));

    for (int e = tid; e < R * 59; e += 512) {
        int r = e / 59, o = e - r * 59;
        const float2* a  = (const float2*)&s.inp[r][0];
        const float2* w2 = (const float2*)&s.wpad[o][0];
        float s0 = 0.f;
        #pragma unroll 4
        for (int j = 0; j < 59; ++j) {
            float2 u = a[j], w = w2[j];
            s0 += u.x * w.x + u.y * w.y;
        }
        dst[r * OFC + half * 59 + o] = (s0 + in_b[o]) * scale;
    }
}

// ---------------------------------------------------------------------------
// phase 2 (blocks 0,1): scores + softmax + colsum row-select + selected row.
// ---------------------------------------------------------------------------
__device__ void td_phase2(int b, int tid, const Params& p, TdSm& s)
{
    const float* base  = p.ws + b * PROJ_STRIDE;
    const float* out_b = b ? p.tdB_out_b : p.tdA_out_b;
    const int wid = tid >> 6, lane = tid & 63;

    for (int e = tid; e < 16 * 59; e += 512) {
        int r = e / 59, j = e - r * 59;
        ((float2*)&s.qpp[r][0])[j] = ((const float2*)(base + r * OFC))[j];
    }
    for (int e = tid; e < TDN * 59; e += 512) {
        int t = e / 59, j = e - t * 59;
        ((float2*)&s.kpp[t][0])[j] = ((const float2*)(base + KP_OFF + t * OFC))[j];
        ((float2*)&s.vpp[t][0])[j] = ((const float2*)(base + VP_OFF + t * OFC))[j];
    }
    __syncthreads();

    if (tid < 16 * TDN) {
        int i = tid / TDN, t = tid - (tid / TDN) * TDN;
        const float2* q = (const float2*)&s.qpp[i][0];
        const float2* k = (const float2*)&s.kpp[t][0];
        float sc = 0.f;
        #pragma unroll 4
        for (int j = 0; j < 59; ++j) {
            float2 u = q[j], v = k[j];
            sc += u.x * v.x + u.y * v.y;
        }
        s.attn[i][t] = sc;
    }
    __syncthreads();

    if (tid < 16) {
        float m = s.attn[tid][0];
        for (int t = 1; t < TDN; ++t) m = fmaxf(m, s.attn[tid][t]);
        float l = 0.f;
        for (int t = 0; t < TDN; ++t) {
            float pp = __expf(s.attn[tid][t] - m);
            s.attn[tid][t] = pp;
            l += pp;
        }
        float inv = 1.f / l;
        for (int t = 0; t < TDN; ++t) s.attn[tid][t] *= inv;
    }
    __syncthreads();

    if (tid < TDN) {
        float a = 0.f;
        for (int i = 0; i < 16; ++i) a += s.attn[i][tid];
        s.acs[tid] = a;
    }
    __syncthreads();

    if (tid < OFC) {
        float a = 0.f;
        for (int t = 0; t < TDN; ++t) a += s.acs[t] * s.vpp[t][tid];
        s.avcs[tid] = a;
    }
    __syncthreads();

    if (tid < OFC) {
        const float2* a  = (const float2*)&s.avcs[0];
        const float2* w2 = (const float2*)&s.owpad[tid][0];
        float a0 = 0.f;
        #pragma unroll 4
        for (int j = 0; j < 59; ++j) {
            float2 u = a[j], v = w2[j];
            a0 += u.x * v.x + u.y * v.y;
        }
        s.colsum[tid] = a0 + 16.f * out_b[tid];
    }
    __syncthreads();

    for (int d = wid; d < 16; d += 8) {
        const float* er = p.x + (1 + d) * WL + (WL - OFC);
        int j0 = lane * 2;
        float sc = 0.f;
        if (j0 < OFC) {
            float2 ev = *(const float2*)(er + j0);
            float2 cv = *(const float2*)(&s.colsum[j0]);
            sc = ev.x * cv.x + ev.y * cv.y;
        }
        sc = wred(sc);
        if (lane == 0) s.Ssum[d] = sc;
    }
    __syncthreads();

    if (tid == 0) {
        int best = 0; float bv = s.Ssum[0];
        for (int i = 1; i < 16; ++i)
            if (s.Ssum[i] > bv) { bv = s.Ssum[i]; best = i; }   // first-max
        s.sel = best;
    }
    __syncthreads();

    if (tid < OFC) {
        float a = 0.f;
        for (int t = 0; t < TDN; ++t) a += s.attn[s.sel][t] * s.vpp[t][tid];
        s.avsel[tid] = a;
    }
    __syncthreads();

    if (tid < OFC) {
        const float2* a  = (const float2*)&s.avsel[0];
        const float2* w2 = (const float2*)&s.owpad[tid][0];
        float a0 = 0.f;
        #pragma unroll 4
        for (int j = 0; j < 59; ++j) {
            float2 u = a[j], v = w2[j];
            a0 += u.x * v.x + u.y * v.y;
        }
        p.ws[(b ? WS_ATT_B : WS_ATT_A) + tid] = a0 + out_b[tid];
    }
}

// ---------------------------------------------------------------------------
// branch prestage (blocks 12..15): everything that doesn't need arow.
// ---------------------------------------------------------------------------
__device__ void br_pre(int br, int tid, const Params& p, BrSm& s)
{
    const bool d_r1 = (br == 0 || br == 3);   // q side rank-1 (data = wA/wB)

    for (int e = tid; e < 16 * OFC; e += 512) {
        int r = e / OFC, c = e - (e / OFC) * OFC;
        s.eeg_s[r][c] = p.x[(1 + r) * WL + (WL - OFC) + c];
    }
    for (int e = tid; e < 768; e += 512) {
        int q = e / 16, r = e % 16;
        s.w_inT[r][q] = p.cm_in_w[br * 768 + e];
    }
    if (tid < 48) s.b_in[tid] = p.cm_in_b[br * 48 + tid];
    if (tid >= 64 && tid < 320) {
        int e = tid - 64;
        s.w_out[e >> 4][e & 15] = p.cm_out_w[br * 256 + e];
    }
    if (tid >= 384 && tid < 400) s.b_out[tid - 384] = p.cm_out_b[br * 16 + (tid - 384)];
    for (int e = tid; e < COUT * 16 * KS; e += 512) s.cw[e] = p.conv_w[br * 1440 + e];
    if (tid >= 400 && tid < 410) s.cb[tid - 400] = p.conv_b[br * COUT + (tid - 400)];
    {
        const float* pvg = (br < 2) ? p.projA_w : p.projB_w;
        if (tid >= 416 && tid < 432) s.pv[tid - 416] = pvg[tid - 416];
    }
    __syncthreads();

    if (tid < 48) {
        float a = 0.f;
        #pragma unroll
        for (int r = 0; r < 16; ++r) a += s.pv[r] * s.w_inT[r][tid];
        s.tv[tid / 16][tid % 16] = a;
    }
    __syncthreads();

    if (d_r1) {
        for (int e = tid; e < 2 * OFC * 16; e += 512) {
            int sec01 = e / (OFC * 16);
            int rem = e - sec01 * OFC * 16;
            int j = rem >> 4, o = rem & 15;
            float a = 0.f;
            #pragma unroll
            for (int r = 0; r < 16; ++r) a += s.eeg_s[r][j] * s.w_inT[r][(1 + sec01) * 16 + o];
            a += s.b_in[(1 + sec01) * 16 + o];
            (sec01 ? &s.vpS[0][0] : &s.kpS[0][0])[j * 17 + o] = a;
        }
        __syncthreads();
        if (tid < OFC) {
            float uu = 0.f, vv = 0.f;
            #pragma unroll
            for (int o = 0; o < 16; ++o) {
                float kv = s.kpS[tid][o];
                uu += s.tv[0][o] * kv;
                vv += s.b_in[o] * kv;
            }
            s.u[tid] = uu; s.v2[tid] = vv;
        }
    } else {
        for (int e = tid; e < OFC * 16; e += 512) {
            int j = e >> 4, o = e & 15;
            float a = 0.f;
            #pragma unroll
            for (int r = 0; r < 16; ++r) a += s.eeg_s[r][j] * s.w_inT[r][o];
            s.qpS[j][o] = (a + s.b_in[o]) * 0.25f;
        }
        __syncthreads();
        if (tid < OFC) {
            float a = 0.f;
            #pragma unroll
            for (int o = 0; o < 16; ++o) a += s.qpS[tid][o] * s.tv[1][o];
            s.a_[tid] = a;
        }
        if (tid >= 128 && tid < 144) {
            int c = tid - 128;
            float A = 0.f, B = 0.f;
            #pragma unroll
            for (int o = 0; o < 16; ++o) {
                A += s.tv[2][o] * s.w_out[c][o];
                B += s.b_in[32 + o] * s.w_out[c][o];
            }
            s.Avec[c] = A;
            s.Bvec[c] = B + s.b_out[c];
        }
        __syncthreads();
        if (tid < COUT * KS) {
            int c = tid / KS, k = tid - (tid / KS) * KS;
            float g = 0.f;
            #pragma unroll
            for (int m = 0; m < 16; ++m) g += s.Avec[m] * s.cw[(c * 16 + m) * KS + k];
            s.Gc[c][k] = g;
        }
        if (tid >= 128 && tid < 128 + COUT) {
            int c = tid - 128;
            float cc = s.cb[c];
            #pragma unroll
            for (int m = 0; m < 16; ++m) {
                float bsum = 0.f;
                #pragma unroll
                for (int k = 0; k < KS; ++k) bsum += s.cw[(c * 16 + m) * KS + k];
                cc += s.Bvec[m] * bsum;
            }
            s.cb2[c] = cc;
        }
    }
}

// ---------------------------------------------------------------------------
// branch main (blocks 12..15), after arow is available.
// ---------------------------------------------------------------------------
__device__ void br_main(int br, int tid, const Params& p, BrSm& s)
{
    const bool d_r1 = (br == 0 || br == 3);
    const float* ar = p.ws + ((br < 2) ? WS_ATT_A : WS_ATT_B);
    if (tid < OFC) s.arow[tid] = ar[tid];
    __syncthreads();

    if (d_r1) {
        const int g = tid >> 7, j = tid & 127;
        float acc[16];
        float m = -INFINITY, l = 0.f;
        #pragma unroll
        for (int r = 0; r < 16; ++r) acc[r] = 0.f;

        if (j < OFC) {
            const float aj = s.arow[j];
            const int t0 = (g * OFC) >> 2, t1 = ((g + 1) * OFC) >> 2;
            for (int t = t0; t < t1; ++t) {
                float sc = 0.25f * fmaf(aj, s.u[t], s.v2[t]);
                float mn = fmaxf(m, sc);
                float c  = __expf(m - mn);
                float pp = __expf(sc - mn);
                l = l * c + pp;
                const float* vr = &s.vpS[t][0];
                #pragma unroll
                for (int r = 0; r < 16; ++r) acc[r] = acc[r] * c + pp * vr[r];
                m = mn;
            }
            s.part_m[g][j] = m;
            s.part_l[g][j] = l;
            #pragma unroll
            for (int r = 0; r < 16; ++r) s.part_acc[g][j][r] = acc[r];
        }
        __syncthreads();

        if (tid < OFC) {
            float m0 = s.part_m[0][tid], m1 = s.part_m[1][tid];
            float m2 = s.part_m[2][tid], m3 = s.part_m[3][tid];
            float mm = fmaxf(fmaxf(m0, m1), fmaxf(m2, m3));
            float c0 = __expf(m0 - mm), c1 = __expf(m1 - mm);
            float c2 = __expf(m2 - mm), c3 = __expf(m3 - mm);
            float ll = c0 * s.part_l[0][tid] + c1 * s.part_l[1][tid]
                     + c2 * s.part_l[2][tid] + c3 * s.part_l[3][tid];
            float inv = 1.f / ll;
            float orow[16];
            #pragma unroll
            for (int r = 0; r < 16; ++r)
                orow[r] = (c0 * s.part_acc[0][tid][r] + c1 * s.part_acc[1][tid][r]
                         + c2 * s.part_acc[2][tid][r] + c3 * s.part_acc[3][tid][r]) * inv;
            for (int c = 0; c < 16; ++c) {
                float a = s.b_out[c];
                #pragma unroll
                for (int d = 0; d < 16; ++d) a += orow[d] * s.w_out[c][d];
                s.o2[tid][c] = a;
            }
        }
        __syncthreads();

        if (tid < COUT * 22) {
            int c = tid / 22, grp = tid - (tid / 22) * 22;
            int pbase = grp * 5;
            float acc5[5];
            #pragma unroll
            for (int i = 0; i < 5; ++i) acc5[i] = s.cb[c];
            for (int mI = 0; mI < 16; ++mI) {
                float win[13];
                #pragma unroll
                for (int t = 0; t < 13; ++t) win[t] = s.o2[pbase + t][mI];
                #pragma unroll
                for (int k = 0; k < KS; ++k) {
                    float wv = s.cw[(c * 16 + mI) * KS + k];
                    #pragma unroll
                    for (int i = 0; i < 5; ++i) acc5[i] += win[i + k] * wv;
                }
            }
            float mx = fmaxf(fmaxf(fmaxf(acc5[0], acc5[1]), fmaxf(acc5[2], acc5[3])), acc5[4]);
            s.y[c][grp] = fmaxf(mx, 0.f);
        }
        __syncthreads();
    } else {
        if (tid < OFC) {
            const float aj = s.a_[tid];
            float m = -INFINITY;
            for (int t = 0; t < OFC; ++t) m = fmaxf(m, aj * s.arow[t]);
            float l = 0.f, d = 0.f;
            for (int t = 0; t < OFC; ++t) {
                float e = __expf(aj * s.arow[t] - m);
                l += e;
                d += e * s.arow[t];
            }
            s.dvec[tid] = d / l;
        }
        __syncthreads();

        if (tid < COUT * 22) {
            int c = tid / 22, grp = tid - (tid / 22) * 22;
            int pbase = grp * 5;
            float win[13];
            #pragma unroll
            for (int t = 0; t < 13; ++t) win[t] = s.dvec[pbase + t];
            float acc5[5];
            #pragma unroll
            for (int i = 0; i < 5; ++i) acc5[i] = s.cb2[c];
            #pragma unroll
            for (int k = 0; k < KS; ++k) {
                float wv = s.Gc[c][k];
                #pragma unroll
                for (int i = 0; i < 5; ++i) acc5[i] += win[i + k] * wv;
            }
            float mx = fmaxf(fmaxf(fmaxf(acc5[0], acc5[1]), fmaxf(acc5[2], acc5[3])), acc5[4]);
            s.y[c][grp] = fmaxf(mx, 0.f);
        }
        __syncthreads();
    }

    if (tid < COUT) {
        float mx = s.y[tid][0];
        for (int g2 = 1; g2 < 22; ++g2) mx = fmaxf(mx, s.y[tid][g2]);
        p.ws[WS_FEATS + br * COUT + tid] = mx;
    }
}

// ---------------------------------------------------------------------------
__global__ __launch_bounds__(512) void fused_net(Params p)
{
    __shared__ Sm sm;
    const int blk = blockIdx.x;
    const int tid = threadIdx.x;
    int* flags = (int*)(p.ws + WS_FLAGS);

    if (blk < 12) {
        td_proj(blk, tid, p, sm.t);
        postM(&flags[blk * 16], tid);                   // proj slot 0..11

        if (blk < 2) {
            // stage out_w while other proj blocks finish
            const float* ow = blk ? p.tdB_out_w : p.tdA_out_w;
            for (int e = tid; e < OFC * 59; e += 512) {
                int o = e / 59, j = e - o * 59;
                ((float2*)&sm.t.owpad[o][0])[j] = ((const float2*)(ow + o * OFC))[j];
            }
            waitM(flags, blk * 6, 6, tid);              // own side's 6 proj slots
            td_phase2(blk, tid, p, sm.t);
            postM(&flags[(12 + blk) * 16], tid);        // attA / attB

            if (blk == 0) {
                waitM(flags, 14, 4, tid);               // 4 feats slots
                // reset all slots for the next replay (safe: every flag read
                // in the system happens-before feats==MAGIC observed here)
                if (tid < NSLOTS)
                    __hip_atomic_store(&flags[tid * 16], 0,
                                       __ATOMIC_RELAXED, __HIP_MEMORY_SCOPE_AGENT);
                __syncthreads();
                if (tid < 40) sm.h.f[tid] = p.ws[WS_FEATS + tid];
                __syncthreads();
                if (tid < 40) {
                    float a = p.fc1_b[tid];
                    for (int k = 0; k < 40; ++k) a += sm.h.f[k] * p.fc1_w[tid * 40 + k];
                    sm.h.h[tid] = 1.f / (1.f + __expf(-a));
                }
                __syncthreads();
                if (tid < 2) {
                    float a = p.fc2_b[tid];
                    for (int k = 0; k < 40; ++k) a += sm.h.h[k] * p.fc2_w[tid * 40 + k];
                    p.out[tid] = 1.f / (1.f + __expf(-a));
                }
            }
        }
    } else {
        const int br = blk - 12;
        br_pre(br, tid, p, sm.b);
        waitM(flags, (br < 2) ? 12 : 13, 1, tid);       // attA or attB
        br_main(br, tid, p, sm.b);
        postM(&flags[(14 + br) * 16], tid);             // feats slot
    }
}

// ---------------------------------------------------------------------------
extern "C" void kernel_launch(void* const* d_in, const int* in_sizes, int n_in,
                              void* d_out, int out_size, void* d_ws, size_t ws_size,
                              hipStream_t stream) {
    Params prm;
    prm.x         = (const float*)d_in[0];
    prm.tdA_in_w  = (const float*)d_in[1];
    prm.tdA_in_b  = (const float*)d_in[2];
    prm.tdA_out_w = (const float*)d_in[3];
    prm.tdA_out_b = (const float*)d_in[4];
    prm.tdB_in_w  = (const float*)d_in[5];
    prm.tdB_in_b  = (const float*)d_in[6];
    prm.tdB_out_w = (const float*)d_in[7];
    prm.tdB_out_b = (const float*)d_in[8];
    prm.cm_in_w   = (const float*)d_in[9];
    prm.cm_in_b   = (const float*)d_in[10];
    prm.cm_out_w  = (const float*)d_in[11];
    prm.cm_out_b  = (const float*)d_in[12];
    prm.projA_w   = (const float*)d_in[13];
    prm.projB_w   = (const float*)d_in[14];
    prm.conv_w    = (const float*)d_in[15];
    prm.conv_b    = (const float*)d_in[16];
    prm.fc1_w     = (const float*)d_in[17];
    prm.fc1_b     = (const float*)d_in[18];
    prm.fc2_w     = (const float*)d_in[19];
    prm.fc2_b     = (const float*)d_in[20];
    prm.ws        = (float*)d_ws;
    prm.out       = (float*)d_out;

    fused_net<<<dim3(16), dim3(512), 0, stream>>>(prm);
}